// Round 6
// baseline (495.742 us; speedup 1.0000x reference)
//
#include <hip/hip_runtime.h>
#include <hip/hip_bf16.h>
#include <cstddef>

#define NB 2
#define SEQ 2048
#define DIMX 4096
#define NH 16
#define NKV 4
#define HD 64
#define LATENT 1024
#define KVD 256
#define QKVN 1536
#define BS (NB*SEQ)
#define SP (SEQ+2)   // padded token rows per batch for conv2 input

typedef __attribute__((ext_vector_type(8))) short short8v;   // 8 bf16 = 4 VGPR
typedef __attribute__((ext_vector_type(4))) float f32x4;
typedef __attribute__((ext_vector_type(4))) unsigned short ushort4v;

static __device__ __forceinline__ unsigned short f2bf(float f) {
    union { float f; unsigned u; } v; v.f = f;
    unsigned r = v.u + 0x7fffu + ((v.u >> 16) & 1u);
    return (unsigned short)(r >> 16);
}

static __device__ __forceinline__ void gload_lds16(const unsigned short* g, unsigned short* l) {
    __builtin_amdgcn_global_load_lds((const __attribute__((address_space(1))) void*)g,
                                     (__attribute__((address_space(3))) void*)l, 16, 0, 0);
}

// ---------------- fp32 -> bf16 cast (vectorized x4) ----------------
__global__ __launch_bounds__(256)
void cast_f2b(const float* __restrict__ in, unsigned short* __restrict__ out, int n4)
{
    const int i = blockIdx.x * 256 + threadIdx.x;
    if (i < n4) {
        const float4 v = *reinterpret_cast<const float4*>(in + (size_t)i * 4);
        ushort4v o = {f2bf(v.x), f2bf(v.y), f2bf(v.z), f2bf(v.w)};
        *reinterpret_cast<ushort4v*>(out + (size_t)i * 4) = o;
    }
}

// ---------------- conv2 weight reorder: wr[o][j*I+c] = w[o][c][j], fp32->bf16 ----------------
__global__ __launch_bounds__(256)
void w3reorder(const float* __restrict__ w, unsigned short* __restrict__ wr, int O, int I)
{
    const int idx = blockIdx.x * 256 + threadIdx.x;
    if (idx < O * I * 3) {
        const int o = idx / (I * 3), rem = idx % (I * 3);
        const int j = rem / I, c = rem % I;
        wr[idx] = f2bf(w[(size_t)o * I * 3 + c * 3 + j]);
    }
}

// ---------------- zero the 2 pad rows per batch of the conv2 input buffers ----------------
__global__ __launch_bounds__(256)
void zero_pad(unsigned short* __restrict__ pq, unsigned short* __restrict__ pk)
{
    const int t = blockIdx.x * 256 + threadIdx.x;
    if (t < 2 * 2 * LATENT) {
        const int b = t / (2 * LATENT), r = (t % (2 * LATENT)) / LATENT, c = t % LATENT;
        pq[((size_t)b * SP + r) * LATENT + c] = 0;
    }
    if (t < 2 * 2 * KVD) {
        const int b = t / (2 * KVD), r = (t % (2 * KVD)) / KVD, c = t % KVD;
        pk[((size_t)b * SP + r) * KVD + c] = 0;
    }
}

// ---------------- bf16 MFMA GEMM: C[M][N] = A[M][K] @ W[N][K]^T (+bias), fp32 out ----------------
template<int CONV>
__global__ __launch_bounds__(256)
void gemm_bf16(const unsigned short* __restrict__ A, const unsigned short* __restrict__ W,
               const float* __restrict__ bias, float* __restrict__ C,
               int M, int N, int K, int Cch)
{
    __shared__ unsigned short Abuf[2][128 * 32];
    __shared__ unsigned short Bbuf[2][128 * 32];
    const int n0 = blockIdx.x * 128, m0 = blockIdx.y * 128;
    const int tid = threadIdx.x;
    const int wave = tid >> 6, lane = tid & 63;
    const int lg = lane >> 4, lr = lane & 15;
    const int wm = (wave & 1) * 64, wn = (wave >> 1) * 64;
    const int sr = wave * 32 + (lane >> 2);
    const int sc = (lane & 3) * 8;
    const int bb = m0 / SEQ, s0 = m0 % SEQ;

    const int NT = K / 32;
    f32x4 acc[4][4];
    #pragma unroll
    for (int i = 0; i < 4; i++)
        #pragma unroll
        for (int j = 0; j < 4; j++) acc[i][j] = (f32x4){0.f, 0.f, 0.f, 0.f};

    auto stage = [&](int buf, int kt) {
        const int k0 = kt * 32;
        const unsigned short* ga0;
        if (!CONV) {
            ga0 = A + (size_t)(m0 + sr) * K + k0 + sc;
        } else {
            const int j = k0 / Cch, c0 = k0 - j * Cch;
            ga0 = A + (size_t)(bb * SP + s0 + j + sr) * Cch + c0 + sc;
        }
        const unsigned short* gb0 = W + (size_t)(n0 + sr) * K + k0 + sc;
        const size_t astep = (size_t)16 * (CONV ? Cch : K);
        #pragma unroll
        for (int i = 0; i < 2; i++) {
            gload_lds16(ga0 + i * astep, &Abuf[buf][(wave * 2 + i) * 512]);
            gload_lds16(gb0 + (size_t)i * 16 * K, &Bbuf[buf][(wave * 2 + i) * 512]);
        }
    };

    stage(0, 0);
    __syncthreads();
    int cur = 0;
    for (int kt = 0; kt < NT; ++kt) {
        if (kt + 1 < NT) stage(cur ^ 1, kt + 1);
        short8v af[4], bf[4];
        #pragma unroll
        for (int mi = 0; mi < 4; mi++)
            af[mi] = *reinterpret_cast<const short8v*>(&Abuf[cur][(wm + mi * 16 + lr) * 32 + lg * 8]);
        #pragma unroll
        for (int ni = 0; ni < 4; ni++)
            bf[ni] = *reinterpret_cast<const short8v*>(&Bbuf[cur][(wn + ni * 16 + lr) * 32 + lg * 8]);
        #pragma unroll
        for (int mi = 0; mi < 4; mi++)
            #pragma unroll
            for (int ni = 0; ni < 4; ni++)
                acc[mi][ni] = __builtin_amdgcn_mfma_f32_16x16x32_bf16(af[mi], bf[ni], acc[mi][ni], 0, 0, 0);
        __syncthreads();
        cur ^= 1;
    }

    #pragma unroll
    for (int ni = 0; ni < 4; ni++) {
        const int col = n0 + wn + ni * 16 + lr;
        const float bv = bias ? bias[col] : 0.f;
        #pragma unroll
        for (int mi = 0; mi < 4; mi++)
            #pragma unroll
            for (int r = 0; r < 4; r++)
                C[(size_t)(m0 + wm + mi * 16 + lg * 4 + r) * N + col] = acc[mi][ni][r] + bv;
    }
}

// ---------------- grouped causal conv1 -> bf16 padded [b][SP][CH] (rows 0,1 zero) ----------------
__global__ __launch_bounds__(256)
void conv1_grouped(const float* __restrict__ qkv, int coloff,
                   const float* __restrict__ w, const float* __restrict__ bias,
                   unsigned short* __restrict__ out, int CH)
{
    const int t0 = blockIdx.x * 64;
    const int b  = blockIdx.y;
    const int g  = blockIdx.z;
    __shared__ float xs[66][64];
    for (int idx = threadIdx.x; idx < 66 * 64; idx += 256) {
        const int i = idx >> 6, ic = idx & 63;
        const int tt = t0 + i - 2;
        xs[i][ic] = (tt >= 0) ? qkv[(size_t)(b * SEQ + tt) * QKVN + coloff + g * 64 + ic] : 0.f;
    }
    __syncthreads();
    const int oc = threadIdx.x & 63;
    const int ibase = (threadIdx.x >> 6) * 16;
    float acc[16];
    const float bv = bias[g * 64 + oc];
    #pragma unroll
    for (int i = 0; i < 16; i++) acc[i] = bv;
    const float* wp = w + (size_t)(g * 64 + oc) * 192;
    for (int ic = 0; ic < 64; ic++) {
        const float w0 = wp[ic * 3 + 0], w1 = wp[ic * 3 + 1], w2 = wp[ic * 3 + 2];
        float xv[18];
        #pragma unroll
        for (int r = 0; r < 18; r++) xv[r] = xs[ibase + r][ic];
        #pragma unroll
        for (int i = 0; i < 16; i++) acc[i] += w0 * xv[i] + w1 * xv[i + 1] + w2 * xv[i + 2];
    }
    #pragma unroll
    for (int i = 0; i < 16; i++)
        out[((size_t)b * SP + 2 + t0 + ibase + i) * CH + g * 64 + oc] = f2bf(acc[i]);
}

// ---------------- head means + shifted-v build (row-major bf16) ----------------
__global__ __launch_bounds__(64)
void meanv_kernel(const float* __restrict__ qkv, float* __restrict__ qmean,
                  float* __restrict__ kmean, unsigned short* __restrict__ vRow)
{
    const int t = blockIdx.x, d = threadIdx.x;
    const int b = t >> 11, s = t & (SEQ - 1);
    const float* row = qkv + (size_t)t * QKVN;
    float qs = 0.f;
    #pragma unroll
    for (int h = 0; h < NH; h++) qs += row[h * 64 + d];
    qmean[t * 64 + d] = qs * (1.f / NH);
    float ks = 0.f;
    #pragma unroll
    for (int h = 0; h < NKV; h++) ks += row[LATENT + h * 64 + d];
    kmean[t * 64 + d] = ks * (1.f / NKV);
    #pragma unroll
    for (int g = 0; g < NKV; g++) {
        const int c = g * 64 + d;
        float v;
        if (c < 128) v = row[LATENT + KVD + c];
        else         v = (s > 0) ? qkv[(size_t)(t - 1) * QKVN + LATENT + KVD + 128 + (c - 128)] : 0.f;
        vRow[((size_t)(b * NKV + g) * SEQ + s) * 64 + d] = f2bf(v);
    }
}

// ---------------- V transpose to d-major: vTb[bg][d][S] ----------------
__global__ __launch_bounds__(256)
void vtrans(const unsigned short* __restrict__ vRow, unsigned short* __restrict__ vTb)
{
    const int s0 = blockIdx.x * 64;
    const int bg = blockIdx.y;
    __shared__ unsigned short t[64][72];
    const int tid = threadIdx.x;
    {
        const int r = tid >> 2, c0 = (tid & 3) * 16;
        const unsigned short* p = vRow + ((size_t)bg * SEQ + s0 + r) * 64 + c0;
        const short8v a = *reinterpret_cast<const short8v*>(p);
        const short8v bv = *reinterpret_cast<const short8v*>(p + 8);
        #pragma unroll
        for (int j = 0; j < 8; j++) { t[r][c0 + j] = (unsigned short)a[j]; t[r][c0 + 8 + j] = (unsigned short)bv[j]; }
    }
    __syncthreads();
    {
        const int d = tid >> 2, ss = (tid & 3) * 16;
        short8v o0, o1;
        #pragma unroll
        for (int j = 0; j < 8; j++) { o0[j] = (short)t[ss + j][d]; o1[j] = (short)t[ss + 8 + j][d]; }
        unsigned short* op = vTb + ((size_t)bg * 64 + d) * SEQ + s0 + ss;
        *reinterpret_cast<short8v*>(op) = o0;
        *reinterpret_cast<short8v*>(op + 8) = o1;
    }
}

// ---------------- +0.5*mean, l2norm, rope -> bf16 (B,H,S,D) ----------------
__global__ __launch_bounds__(64)
void qk_final(const float* __restrict__ qc2, const float* __restrict__ kc2,
              const float* __restrict__ qmean, const float* __restrict__ kmean,
              const float* __restrict__ key_temp,
              unsigned short* __restrict__ qTb, unsigned short* __restrict__ kTb)
{
    const int t = blockIdx.x, hh = blockIdx.y, d = threadIdx.x;
    const int b = t >> 11, s = t & (SEQ - 1);
    float val;
    if (hh < NH) val = qc2[(size_t)t * LATENT + hh * 64 + d]        + 0.5f * kmean[t * 64 + d];
    else         val = kc2[(size_t)t * KVD    + (hh - NH) * 64 + d] + 0.5f * qmean[t * 64 + d];
    float ss = val * val;
    #pragma unroll
    for (int off = 32; off >= 1; off >>= 1) ss += __shfl_xor(ss, off);
    const float n = sqrtf(ss);
    val = val / fmaxf(n, 1e-12f);
    if (hh >= NH) val *= key_temp[0];
    const int i = d >> 1;
    const float inv = powf(10000.f, -(float)(2 * i) * (1.f / HD));
    const float ang = (float)s * inv;
    const float cv = cosf(ang), sv = sinf(ang);
    const float partner = __shfl_xor(val, 1);
    const float x1 = (d & 1) ? partner : val;
    const float x2 = (d & 1) ? val : partner;
    const float o = (d & 1) ? (x1 * sv + x2 * cv) : (x1 * cv - x2 * sv);
    if (hh < NH) qTb[((size_t)(b * NH + hh) * SEQ + s) * 64 + d] = f2bf(o);
    else         kTb[((size_t)(b * NKV + (hh - NH)) * SEQ + s) * 64 + d] = f2bf(o);
}

// ---------------- MFMA causal GQA attention, per-wave q-tile + reg double-buffered K/V ----------------
// Each wave owns one 32-row q-tile; no inter-wave sync. Tile c+1's K/V fragments are
// prefetched into the alternate register set while tile c computes (2-unrolled, named bufs).
__global__ __launch_bounds__(256)
void attn_mfma(const unsigned short* __restrict__ qTb, const unsigned short* __restrict__ kTb,
               const unsigned short* __restrict__ vTb, unsigned short* __restrict__ attn_out)
{
    const int tid = threadIdx.x;
    const int wave = tid >> 6, lane = tid & 63;
    const int lg = lane >> 4, lr = lane & 15;
    const int gq = blockIdx.x * 4 + wave;    // 0..63
    const int qt = 63 - gq;                  // longest tiles first
    const int bh = blockIdx.y;
    const int b = bh >> 4, h = bh & 15, g = h >> 2;
    const int q0 = qt * 32;

    __shared__ __align__(16) unsigned short PldsAll[4][2][16][40];
    unsigned short (*Plds)[16][40] = PldsAll[wave];

    short8v qf[2][2];
    const unsigned short* qbase = qTb + ((size_t)(b * NH + h) * SEQ + q0) * 64;
    #pragma unroll
    for (int mf = 0; mf < 2; mf++)
        #pragma unroll
        for (int dc = 0; dc < 2; dc++)
            qf[mf][dc] = *reinterpret_cast<const short8v*>(qbase + (size_t)(mf * 16 + lr) * 64 + dc * 32 + lg * 8);

    f32x4 acc[2][4];
    float lsum[2][4];
    #pragma unroll
    for (int mf = 0; mf < 2; mf++) {
        #pragma unroll
        for (int dt = 0; dt < 4; dt++) acc[mf][dt] = (f32x4){0.f, 0.f, 0.f, 0.f};
        #pragma unroll
        for (int r = 0; r < 4; r++) lsum[mf][r] = 0.f;
    }

    const unsigned short* kbase = kTb + (size_t)(b * NKV + g) * SEQ * 64;
    const unsigned short* vbase = vTb + (size_t)(b * NKV + g) * 64 * SEQ;
    const float EC = 0.125f * 1.44269504f;

    auto loadKV = [&](short8v (&kf)[2][2], short8v (&vf)[4], int c) {
        const int k0 = c * 32;
        #pragma unroll
        for (int kt = 0; kt < 2; kt++)
            #pragma unroll
            for (int dc = 0; dc < 2; dc++)
                kf[kt][dc] = *reinterpret_cast<const short8v*>(kbase + (size_t)(k0 + kt * 16 + lr) * 64 + dc * 32 + lg * 8);
        #pragma unroll
        for (int dt = 0; dt < 4; dt++)
            vf[dt] = *reinterpret_cast<const short8v*>(vbase + (size_t)(dt * 16 + lr) * SEQ + k0 + lg * 8);
    };

    auto computeT = [&](short8v (&kf)[2][2], short8v (&vf)[4], int c) {
        const int k0 = c * 32;
        f32x4 S[2][2];
        #pragma unroll
        for (int mf = 0; mf < 2; mf++)
            #pragma unroll
            for (int kt = 0; kt < 2; kt++) {
                f32x4 z = (f32x4){0.f, 0.f, 0.f, 0.f};
                z = __builtin_amdgcn_mfma_f32_16x16x32_bf16(qf[mf][0], kf[kt][0], z, 0, 0, 0);
                S[mf][kt] = __builtin_amdgcn_mfma_f32_16x16x32_bf16(qf[mf][1], kf[kt][1], z, 0, 0, 0);
            }
        const bool diag = (c == qt);
        #pragma unroll
        for (int mf = 0; mf < 2; mf++)
            #pragma unroll
            for (int kt = 0; kt < 2; kt++)
                #pragma unroll
                for (int r = 0; r < 4; r++) {
                    float p = exp2f(S[mf][kt][r] * EC);
                    if (diag) {
                        const int q = q0 + mf * 16 + lg * 4 + r;
                        const int key = k0 + kt * 16 + lr;
                        if (key > q) p = 0.f;
                    }
                    lsum[mf][r] += p;
                    Plds[mf][lg * 4 + r][kt * 16 + lr] = f2bf(p);
                }
        #pragma unroll
        for (int mf = 0; mf < 2; mf++) {
            const short8v pa = *reinterpret_cast<const short8v*>(&Plds[mf][lr][lg * 8]);
            #pragma unroll
            for (int dt = 0; dt < 4; dt++)
                acc[mf][dt] = __builtin_amdgcn_mfma_f32_16x16x32_bf16(pa, vf[dt], acc[mf][dt], 0, 0, 0);
        }
    };

    short8v kA[2][2], vA[4], kB[2][2], vB[4];
    loadKV(kA, vA, 0);
    for (int c = 0; c <= qt; c += 2) {
        if (c + 1 <= qt) loadKV(kB, vB, c + 1);
        computeT(kA, vA, c);
        if (c + 1 > qt) break;
        if (c + 2 <= qt) loadKV(kA, vA, c + 2);
        computeT(kB, vB, c + 1);
    }

    float invl[2][4];
    #pragma unroll
    for (int mf = 0; mf < 2; mf++)
        #pragma unroll
        for (int r = 0; r < 4; r++) {
            float s = lsum[mf][r];
            s += __shfl_xor(s, 1); s += __shfl_xor(s, 2);
            s += __shfl_xor(s, 4); s += __shfl_xor(s, 8);
            invl[mf][r] = 1.f / s;
        }

    #pragma unroll
    for (int mf = 0; mf < 2; mf++)
        #pragma unroll
        for (int dt = 0; dt < 4; dt++)
            #pragma unroll
            for (int r = 0; r < 4; r++) {
                const int q = q0 + mf * 16 + lg * 4 + r;
                attn_out[(size_t)(b * SEQ + q) * LATENT + h * 64 + dt * 16 + lr] = f2bf(acc[mf][dt][r] * invl[mf][r]);
            }
}

extern "C" void kernel_launch(void* const* d_in, const int* in_sizes, int n_in,
                              void* d_out, int out_size, void* d_ws, size_t ws_size,
                              hipStream_t stream)
{
    const float* x       = (const float*)d_in[0];
    const float* w_qkv   = (const float*)d_in[1];
    const float* w_o     = (const float*)d_in[2];
    const float* qc1_w   = (const float*)d_in[3];
    const float* qc1_b   = (const float*)d_in[4];
    const float* qc2_w   = (const float*)d_in[5];
    const float* qc2_b   = (const float*)d_in[6];
    const float* kc1_w   = (const float*)d_in[7];
    const float* kc1_b   = (const float*)d_in[8];
    const float* kc2_w   = (const float*)d_in[9];
    const float* kc2_b   = (const float*)d_in[10];
    const float* key_temp = (const float*)d_in[11];

    // --- workspace layout (aliased by lifetime) ---
    char* wsb = (char*)d_ws;
    float* qkv = (float*)wsb;                 wsb += (size_t)BS * QKVN * 4;
    float* qc2 = qkv;
    float* kc2 = (float*)((char*)qkv + (size_t)BS * LATENT * 4);
    unsigned short* pq  = (unsigned short*)wsb;  wsb += (size_t)NB * SP * LATENT * 2;
    unsigned short* pk  = (unsigned short*)wsb;  wsb += (size_t)NB * SP * KVD * 2;
    float* qmean = (float*)wsb;  wsb += (size_t)BS * HD * 4;
    float* kmean = (float*)wsb;  wsb += (size_t)BS * HD * 4;
    unsigned short* qTb  = (unsigned short*)wsb;  wsb += (size_t)BS * LATENT * 2;
    unsigned short* kTb  = (unsigned short*)wsb;  wsb += (size_t)BS * KVD * 2;
    unsigned short* vRow = (unsigned short*)wsb;  wsb += (size_t)BS * KVD * 2;
    unsigned short* vTb  = (unsigned short*)wsb;  wsb += (size_t)BS * KVD * 2;
    unsigned short* xb   = (unsigned short*)wsb;  wsb += (size_t)BS * DIMX * 2;
    unsigned short* attnb  = xb;
    unsigned short* qc2wr  = (unsigned short*)((char*)xb + (size_t)BS * LATENT * 2);
    unsigned short* kc2wr  = (unsigned short*)((char*)qc2wr + (size_t)LATENT * LATENT * 3 * 2);
    unsigned short* wqkvb = (unsigned short*)wsb;  wsb += (size_t)QKVN * DIMX * 2;
    unsigned short* wob   = wqkvb;

    float* outp = (float*)d_out;

    cast_f2b<<<dim3(BS * DIMX / 4 / 256), 256, 0, stream>>>(x, xb, BS * DIMX / 4);
    cast_f2b<<<dim3(QKVN * DIMX / 4 / 256), 256, 0, stream>>>(w_qkv, wqkvb, QKVN * DIMX / 4);
    gemm_bf16<0><<<dim3(QKVN / 128, BS / 128), 256, 0, stream>>>(xb, wqkvb, nullptr, qkv, BS, QKVN, DIMX, 0);
    cast_f2b<<<dim3(DIMX * LATENT / 4 / 256), 256, 0, stream>>>(w_o, wob, DIMX * LATENT / 4);
    w3reorder<<<dim3((LATENT * LATENT * 3 + 255) / 256), 256, 0, stream>>>(qc2_w, qc2wr, LATENT, LATENT);
    w3reorder<<<dim3((KVD * KVD * 3 + 255) / 256), 256, 0, stream>>>(kc2_w, kc2wr, KVD, KVD);
    zero_pad<<<dim3(16), 256, 0, stream>>>(pq, pk);
    meanv_kernel<<<dim3(BS), 64, 0, stream>>>(qkv, qmean, kmean, vRow);
    vtrans<<<dim3(SEQ / 64, NB * NKV), 256, 0, stream>>>(vRow, vTb);
    conv1_grouped<<<dim3(SEQ / 64, NB, NH),  256, 0, stream>>>(qkv, 0,      qc1_w, qc1_b, pq, LATENT);
    conv1_grouped<<<dim3(SEQ / 64, NB, NKV), 256, 0, stream>>>(qkv, LATENT, kc1_w, kc1_b, pk, KVD);
    gemm_bf16<1><<<dim3(LATENT / 128, BS / 128), 256, 0, stream>>>(pq, qc2wr, qc2_b, qc2, BS, LATENT, LATENT * 3, LATENT);
    gemm_bf16<1><<<dim3(KVD / 128,    BS / 128), 256, 0, stream>>>(pk, kc2wr, kc2_b, kc2, BS, KVD,    KVD * 3,    KVD);
    qk_final<<<dim3(BS, NH + NKV), 64, 0, stream>>>(qc2, kc2, qmean, kmean, key_temp, qTb, kTb);
    attn_mfma<<<dim3(SEQ / 32 / 4, NB * NH), 256, 0, stream>>>(qTb, kTb, vTb, attnb);
    gemm_bf16<0><<<dim3(DIMX / 128, BS / 128), 256, 0, stream>>>(attnb, wob, nullptr, outp, BS, DIMX, LATENT, 0);
}

// Round 7
// 488.164 us; speedup vs baseline: 1.0155x; 1.0155x over previous
//
#include <hip/hip_runtime.h>
#include <hip/hip_bf16.h>
#include <cstddef>

#define NB 2
#define SEQ 2048
#define DIMX 4096
#define NH 16
#define NKV 4
#define HD 64
#define LATENT 1024
#define KVD 256
#define QKVN 1536
#define BS (NB*SEQ)
#define SP (SEQ+2)   // padded token rows per batch for conv2 input

typedef __attribute__((ext_vector_type(8))) short short8v;   // 8 bf16 = 4 VGPR
typedef __attribute__((ext_vector_type(4))) float f32x4;
typedef __attribute__((ext_vector_type(4))) unsigned short ushort4v;
typedef __attribute__((ext_vector_type(4))) unsigned int uint4v;

static __device__ __forceinline__ unsigned short f2bf(float f) {
    union { float f; unsigned u; } v; v.f = f;
    unsigned r = v.u + 0x7fffu + ((v.u >> 16) & 1u);
    return (unsigned short)(r >> 16);
}

static __device__ __forceinline__ unsigned cvt_pk_bf16(float lo, float hi) {
    unsigned r;
    asm("v_cvt_pk_bf16_f32 %0, %1, %2" : "=v"(r) : "v"(lo), "v"(hi));
    return r;
}

static __device__ __forceinline__ void gload_lds16(const unsigned short* g, unsigned short* l) {
    __builtin_amdgcn_global_load_lds((const __attribute__((address_space(1))) void*)g,
                                     (__attribute__((address_space(3))) void*)l, 16, 0, 0);
}

// ---------------- fp32 -> bf16 cast (vectorized x4) ----------------
__global__ __launch_bounds__(256)
void cast_f2b(const float* __restrict__ in, unsigned short* __restrict__ out, int n4)
{
    const int i = blockIdx.x * 256 + threadIdx.x;
    if (i < n4) {
        const float4 v = *reinterpret_cast<const float4*>(in + (size_t)i * 4);
        ushort4v o = {f2bf(v.x), f2bf(v.y), f2bf(v.z), f2bf(v.w)};
        *reinterpret_cast<ushort4v*>(out + (size_t)i * 4) = o;
    }
}

// ---------------- conv2 weight reorder: wr[o][j*I+c] = w[o][c][j], fp32->bf16 ----------------
__global__ __launch_bounds__(256)
void w3reorder(const float* __restrict__ w, unsigned short* __restrict__ wr, int O, int I)
{
    const int idx = blockIdx.x * 256 + threadIdx.x;
    if (idx < O * I * 3) {
        const int o = idx / (I * 3), rem = idx % (I * 3);
        const int j = rem / I, c = rem % I;
        wr[idx] = f2bf(w[(size_t)o * I * 3 + c * 3 + j]);
    }
}

// ---------------- zero the 2 pad rows per batch of the conv2 input buffers ----------------
__global__ __launch_bounds__(256)
void zero_pad(unsigned short* __restrict__ pq, unsigned short* __restrict__ pk)
{
    const int t = blockIdx.x * 256 + threadIdx.x;
    if (t < 2 * 2 * LATENT) {
        const int b = t / (2 * LATENT), r = (t % (2 * LATENT)) / LATENT, c = t % LATENT;
        pq[((size_t)b * SP + r) * LATENT + c] = 0;
    }
    if (t < 2 * 2 * KVD) {
        const int b = t / (2 * KVD), r = (t % (2 * KVD)) / KVD, c = t % KVD;
        pk[((size_t)b * SP + r) * KVD + c] = 0;
    }
}

// ---------------- bf16 MFMA GEMM: C[M][N] = A[M][K] @ W[N][K]^T (+bias), fp32 out ----------------
template<int CONV>
__global__ __launch_bounds__(256)
void gemm_bf16(const unsigned short* __restrict__ A, const unsigned short* __restrict__ W,
               const float* __restrict__ bias, float* __restrict__ C,
               int M, int N, int K, int Cch)
{
    __shared__ unsigned short Abuf[2][128 * 32];
    __shared__ unsigned short Bbuf[2][128 * 32];
    const int n0 = blockIdx.x * 128, m0 = blockIdx.y * 128;
    const int tid = threadIdx.x;
    const int wave = tid >> 6, lane = tid & 63;
    const int lg = lane >> 4, lr = lane & 15;
    const int wm = (wave & 1) * 64, wn = (wave >> 1) * 64;
    const int sr = wave * 32 + (lane >> 2);
    const int sc = (lane & 3) * 8;
    const int bb = m0 / SEQ, s0 = m0 % SEQ;

    const int NT = K / 32;
    f32x4 acc[4][4];
    #pragma unroll
    for (int i = 0; i < 4; i++)
        #pragma unroll
        for (int j = 0; j < 4; j++) acc[i][j] = (f32x4){0.f, 0.f, 0.f, 0.f};

    auto stage = [&](int buf, int kt) {
        const int k0 = kt * 32;
        const unsigned short* ga0;
        if (!CONV) {
            ga0 = A + (size_t)(m0 + sr) * K + k0 + sc;
        } else {
            const int j = k0 / Cch, c0 = k0 - j * Cch;
            ga0 = A + (size_t)(bb * SP + s0 + j + sr) * Cch + c0 + sc;
        }
        const unsigned short* gb0 = W + (size_t)(n0 + sr) * K + k0 + sc;
        const size_t astep = (size_t)16 * (CONV ? Cch : K);
        #pragma unroll
        for (int i = 0; i < 2; i++) {
            gload_lds16(ga0 + i * astep, &Abuf[buf][(wave * 2 + i) * 512]);
            gload_lds16(gb0 + (size_t)i * 16 * K, &Bbuf[buf][(wave * 2 + i) * 512]);
        }
    };

    stage(0, 0);
    __syncthreads();
    int cur = 0;
    for (int kt = 0; kt < NT; ++kt) {
        if (kt + 1 < NT) stage(cur ^ 1, kt + 1);
        short8v af[4], bf[4];
        #pragma unroll
        for (int mi = 0; mi < 4; mi++)
            af[mi] = *reinterpret_cast<const short8v*>(&Abuf[cur][(wm + mi * 16 + lr) * 32 + lg * 8]);
        #pragma unroll
        for (int ni = 0; ni < 4; ni++)
            bf[ni] = *reinterpret_cast<const short8v*>(&Bbuf[cur][(wn + ni * 16 + lr) * 32 + lg * 8]);
        #pragma unroll
        for (int mi = 0; mi < 4; mi++)
            #pragma unroll
            for (int ni = 0; ni < 4; ni++)
                acc[mi][ni] = __builtin_amdgcn_mfma_f32_16x16x32_bf16(af[mi], bf[ni], acc[mi][ni], 0, 0, 0);
        __syncthreads();
        cur ^= 1;
    }

    #pragma unroll
    for (int ni = 0; ni < 4; ni++) {
        const int col = n0 + wn + ni * 16 + lr;
        const float bv = bias ? bias[col] : 0.f;
        #pragma unroll
        for (int mi = 0; mi < 4; mi++)
            #pragma unroll
            for (int r = 0; r < 4; r++)
                C[(size_t)(m0 + wm + mi * 16 + lg * 4 + r) * N + col] = acc[mi][ni][r] + bv;
    }
}

// ---------------- grouped causal conv1 -> bf16 padded [b][SP][CH] (rows 0,1 zero) ----------------
__global__ __launch_bounds__(256)
void conv1_grouped(const float* __restrict__ qkv, int coloff,
                   const float* __restrict__ w, const float* __restrict__ bias,
                   unsigned short* __restrict__ out, int CH)
{
    const int t0 = blockIdx.x * 64;
    const int b  = blockIdx.y;
    const int g  = blockIdx.z;
    __shared__ float xs[66][64];
    for (int idx = threadIdx.x; idx < 66 * 64; idx += 256) {
        const int i = idx >> 6, ic = idx & 63;
        const int tt = t0 + i - 2;
        xs[i][ic] = (tt >= 0) ? qkv[(size_t)(b * SEQ + tt) * QKVN + coloff + g * 64 + ic] : 0.f;
    }
    __syncthreads();
    const int oc = threadIdx.x & 63;
    const int ibase = (threadIdx.x >> 6) * 16;
    float acc[16];
    const float bv = bias[g * 64 + oc];
    #pragma unroll
    for (int i = 0; i < 16; i++) acc[i] = bv;
    const float* wp = w + (size_t)(g * 64 + oc) * 192;
    for (int ic = 0; ic < 64; ic++) {
        const float w0 = wp[ic * 3 + 0], w1 = wp[ic * 3 + 1], w2 = wp[ic * 3 + 2];
        float xv[18];
        #pragma unroll
        for (int r = 0; r < 18; r++) xv[r] = xs[ibase + r][ic];
        #pragma unroll
        for (int i = 0; i < 16; i++) acc[i] += w0 * xv[i] + w1 * xv[i + 1] + w2 * xv[i + 2];
    }
    #pragma unroll
    for (int i = 0; i < 16; i++)
        out[((size_t)b * SP + 2 + t0 + ibase + i) * CH + g * 64 + oc] = f2bf(acc[i]);
}

// ---------------- head means + shifted-v build (row-major bf16) ----------------
__global__ __launch_bounds__(64)
void meanv_kernel(const float* __restrict__ qkv, float* __restrict__ qmean,
                  float* __restrict__ kmean, unsigned short* __restrict__ vRow)
{
    const int t = blockIdx.x, d = threadIdx.x;
    const int b = t >> 11, s = t & (SEQ - 1);
    const float* row = qkv + (size_t)t * QKVN;
    float qs = 0.f;
    #pragma unroll
    for (int h = 0; h < NH; h++) qs += row[h * 64 + d];
    qmean[t * 64 + d] = qs * (1.f / NH);
    float ks = 0.f;
    #pragma unroll
    for (int h = 0; h < NKV; h++) ks += row[LATENT + h * 64 + d];
    kmean[t * 64 + d] = ks * (1.f / NKV);
    #pragma unroll
    for (int g = 0; g < NKV; g++) {
        const int c = g * 64 + d;
        float v;
        if (c < 128) v = row[LATENT + KVD + c];
        else         v = (s > 0) ? qkv[(size_t)(t - 1) * QKVN + LATENT + KVD + 128 + (c - 128)] : 0.f;
        vRow[((size_t)(b * NKV + g) * SEQ + s) * 64 + d] = f2bf(v);
    }
}

// ---------------- V transpose to d-major: vTb[bg][d][S] ----------------
__global__ __launch_bounds__(256)
void vtrans(const unsigned short* __restrict__ vRow, unsigned short* __restrict__ vTb)
{
    const int s0 = blockIdx.x * 64;
    const int bg = blockIdx.y;
    __shared__ unsigned short t[64][72];
    const int tid = threadIdx.x;
    {
        const int r = tid >> 2, c0 = (tid & 3) * 16;
        const unsigned short* p = vRow + ((size_t)bg * SEQ + s0 + r) * 64 + c0;
        const short8v a = *reinterpret_cast<const short8v*>(p);
        const short8v bv = *reinterpret_cast<const short8v*>(p + 8);
        #pragma unroll
        for (int j = 0; j < 8; j++) { t[r][c0 + j] = (unsigned short)a[j]; t[r][c0 + 8 + j] = (unsigned short)bv[j]; }
    }
    __syncthreads();
    {
        const int d = tid >> 2, ss = (tid & 3) * 16;
        short8v o0, o1;
        #pragma unroll
        for (int j = 0; j < 8; j++) { o0[j] = (short)t[ss + j][d]; o1[j] = (short)t[ss + 8 + j][d]; }
        unsigned short* op = vTb + ((size_t)bg * 64 + d) * SEQ + s0 + ss;
        *reinterpret_cast<short8v*>(op) = o0;
        *reinterpret_cast<short8v*>(op + 8) = o1;
    }
}

// ---------------- +0.5*mean, l2norm, rope -> bf16 (B,H,S,D) ----------------
__global__ __launch_bounds__(64)
void qk_final(const float* __restrict__ qc2, const float* __restrict__ kc2,
              const float* __restrict__ qmean, const float* __restrict__ kmean,
              const float* __restrict__ key_temp,
              unsigned short* __restrict__ qTb, unsigned short* __restrict__ kTb)
{
    const int t = blockIdx.x, hh = blockIdx.y, d = threadIdx.x;
    const int b = t >> 11, s = t & (SEQ - 1);
    float val;
    if (hh < NH) val = qc2[(size_t)t * LATENT + hh * 64 + d]        + 0.5f * kmean[t * 64 + d];
    else         val = kc2[(size_t)t * KVD    + (hh - NH) * 64 + d] + 0.5f * qmean[t * 64 + d];
    float ss = val * val;
    #pragma unroll
    for (int off = 32; off >= 1; off >>= 1) ss += __shfl_xor(ss, off);
    const float n = sqrtf(ss);
    val = val / fmaxf(n, 1e-12f);
    if (hh >= NH) val *= key_temp[0];
    const int i = d >> 1;
    const float inv = powf(10000.f, -(float)(2 * i) * (1.f / HD));
    const float ang = (float)s * inv;
    const float cv = cosf(ang), sv = sinf(ang);
    const float partner = __shfl_xor(val, 1);
    const float x1 = (d & 1) ? partner : val;
    const float x2 = (d & 1) ? val : partner;
    const float o = (d & 1) ? (x1 * sv + x2 * cv) : (x1 * cv - x2 * sv);
    if (hh < NH) qTb[((size_t)(b * NH + hh) * SEQ + s) * 64 + d] = f2bf(o);
    else         kTb[((size_t)(b * NKV + (hh - NH)) * SEQ + s) * 64 + d] = f2bf(o);
}

// ---------------- MFMA causal GQA attention: swapped QK^T, no LDS, split-K partials ----------------
// Wave sl of block (x=63-qt, bh) handles key-tiles c ≡ sl (mod 4) of q-tile qt.
// Swapped QK (mfma(K,Q)) puts P for q=lane&15 in-lane; cvt_pk + shfl builds the PV A-frag.
// Partials (num bf16 [32][64], den f32 [32]) written to global; attn_reduce merges.
__global__ __launch_bounds__(256)
void attn_mfma(const unsigned short* __restrict__ qTb, const unsigned short* __restrict__ kTb,
               const unsigned short* __restrict__ vTb,
               unsigned short* __restrict__ pnum, float* __restrict__ pden)
{
    const int tid = threadIdx.x;
    const int sl = tid >> 6, lane = tid & 63;
    const int lg = lane >> 4, lr = lane & 15;
    const int qt = 63 - blockIdx.x;          // longest tiles first
    const int bh = blockIdx.y;
    const int b = bh >> 4, h = bh & 15, g = h >> 2;
    const int q0 = qt * 32;

    short8v qf[2][2];
    const unsigned short* qbase = qTb + ((size_t)(b * NH + h) * SEQ + q0) * 64;
    #pragma unroll
    for (int mf = 0; mf < 2; mf++)
        #pragma unroll
        for (int dc = 0; dc < 2; dc++)
            qf[mf][dc] = *reinterpret_cast<const short8v*>(qbase + (size_t)(mf * 16 + lr) * 64 + dc * 32 + lg * 8);

    f32x4 acc[2][4];
    float lsum[2] = {0.f, 0.f};
    #pragma unroll
    for (int mf = 0; mf < 2; mf++)
        #pragma unroll
        for (int dt = 0; dt < 4; dt++) acc[mf][dt] = (f32x4){0.f, 0.f, 0.f, 0.f};

    const unsigned short* kbase = kTb + (size_t)(b * NKV + g) * SEQ * 64;
    const unsigned short* vbase = vTb + (size_t)(b * NKV + g) * 64 * SEQ;
    const float EC = 0.125f * 1.44269504f;
    const int src01 = ((lg & 1) << 5) + lr;   // source lane for words 0,1
    const int src23 = src01 + 16;             // source lane for words 2,3
    const bool hi = (lg >= 2);

    for (int c = sl; c <= qt; c += 4) {
        const int k0 = c * 32;
        short8v kf[2][2];
        #pragma unroll
        for (int kt = 0; kt < 2; kt++)
            #pragma unroll
            for (int dc = 0; dc < 2; dc++)
                kf[kt][dc] = *reinterpret_cast<const short8v*>(kbase + (size_t)(k0 + kt * 16 + lr) * 64 + dc * 32 + lg * 8);
        short8v vf[4];
        #pragma unroll
        for (int dt = 0; dt < 4; dt++)
            vf[dt] = *reinterpret_cast<const short8v*>(vbase + (size_t)(dt * 16 + lr) * SEQ + k0 + lg * 8);

        const bool diag = (c == qt);
        #pragma unroll
        for (int mf = 0; mf < 2; mf++) {
            // swapped QK^T: S^T tile, lane holds keys {k0+kt*16+4lg+r} for q = q0+mf*16+lr
            f32x4 z0 = (f32x4){0.f, 0.f, 0.f, 0.f}, z1 = (f32x4){0.f, 0.f, 0.f, 0.f};
            z0 = __builtin_amdgcn_mfma_f32_16x16x32_bf16(kf[0][0], qf[mf][0], z0, 0, 0, 0);
            z0 = __builtin_amdgcn_mfma_f32_16x16x32_bf16(kf[0][1], qf[mf][1], z0, 0, 0, 0);
            z1 = __builtin_amdgcn_mfma_f32_16x16x32_bf16(kf[1][0], qf[mf][0], z1, 0, 0, 0);
            z1 = __builtin_amdgcn_mfma_f32_16x16x32_bf16(kf[1][1], qf[mf][1], z1, 0, 0, 0);
            float p0[4], p1[4];
            #pragma unroll
            for (int r = 0; r < 4; r++) {
                p0[r] = exp2f(z0[r] * EC);
                p1[r] = exp2f(z1[r] * EC);
            }
            if (diag) {
                const int q = q0 + mf * 16 + lr;
                #pragma unroll
                for (int r = 0; r < 4; r++) {
                    if (k0 + 4 * lg + r > q)      p0[r] = 0.f;
                    if (k0 + 16 + 4 * lg + r > q) p1[r] = 0.f;
                }
            }
            lsum[mf] += (p0[0] + p0[1]) + (p0[2] + p0[3]) + (p1[0] + p1[1]) + (p1[2] + p1[3]);
            const unsigned W00 = cvt_pk_bf16(p0[0], p0[1]);
            const unsigned W01 = cvt_pk_bf16(p0[2], p0[3]);
            const unsigned W10 = cvt_pk_bf16(p1[0], p1[1]);
            const unsigned W11 = cvt_pk_bf16(p1[2], p1[3]);
            // redistribute: target word w of lane(lg,lr) = keys 8lg+2w,+1
            const unsigned a0 = __shfl(W00, src01), b0 = __shfl(W10, src01);
            const unsigned a1 = __shfl(W01, src01), b1 = __shfl(W11, src01);
            const unsigned a2 = __shfl(W00, src23), b2 = __shfl(W10, src23);
            const unsigned a3 = __shfl(W01, src23), b3 = __shfl(W11, src23);
            uint4v pw;
            pw.x = hi ? b0 : a0;
            pw.y = hi ? b1 : a1;
            pw.z = hi ? b2 : a2;
            pw.w = hi ? b3 : a3;
            const short8v pa = __builtin_bit_cast(short8v, pw);
            #pragma unroll
            for (int dt = 0; dt < 4; dt++)
                acc[mf][dt] = __builtin_amdgcn_mfma_f32_16x16x32_bf16(pa, vf[dt], acc[mf][dt], 0, 0, 0);
        }
    }

    // full per-q denominators (sum over the 4 lane-groups)
    float den0 = lsum[0];
    den0 += __shfl_xor(den0, 16); den0 += __shfl_xor(den0, 32);
    float den1 = lsum[1];
    den1 += __shfl_xor(den1, 16); den1 += __shfl_xor(den1, 32);

    const int base = (bh * 64 + qt) * 4 + sl;
    if (lg == 0) {
        pden[base * 32 + lr] = den0;
        pden[base * 32 + 16 + lr] = den1;
    }
    unsigned short* np = pnum + (size_t)base * 2048;
    #pragma unroll
    for (int mf = 0; mf < 2; mf++)
        #pragma unroll
        for (int dt = 0; dt < 4; dt++)
            #pragma unroll
            for (int r = 0; r < 4; r++)
                np[(mf * 16 + 4 * lg + r) * 64 + dt * 16 + lr] = f2bf(acc[mf][dt][r]);
}

// ---------------- merge split-K partials -> bf16 attn output ----------------
__global__ __launch_bounds__(256)
void attn_reduce(const unsigned short* __restrict__ pnum, const float* __restrict__ pden,
                 unsigned short* __restrict__ attnb)
{
    const int idx = blockIdx.x * 256 + threadIdx.x;   // 524288 total
    const int d0 = (idx & 7) * 8;
    const int qr = (idx >> 3) & 31;
    const int qt = (idx >> 8) & 63;
    const int bh = idx >> 14;
    const int base = (bh * 64 + qt) * 4;
    float s[8] = {0.f, 0.f, 0.f, 0.f, 0.f, 0.f, 0.f, 0.f};
    float den = 0.f;
    #pragma unroll
    for (int sl = 0; sl < 4; sl++) {
        den += pden[(base + sl) * 32 + qr];
        const short8v nv = *reinterpret_cast<const short8v*>(pnum + (size_t)(base + sl) * 2048 + qr * 64 + d0);
        #pragma unroll
        for (int j = 0; j < 8; j++) {
            union { unsigned u; float f; } t;
            t.u = ((unsigned)(unsigned short)nv[j]) << 16;
            s[j] += t.f;
        }
    }
    const float inv = 1.f / den;
    const int q = qt * 32 + qr;
    const int b = bh >> 4, h = bh & 15;
    short8v ov;
    #pragma unroll
    for (int j = 0; j < 8; j++) ov[j] = (short)f2bf(s[j] * inv);
    *reinterpret_cast<short8v*>(attnb + (size_t)(b * SEQ + q) * LATENT + h * 64 + d0) = ov;
}

extern "C" void kernel_launch(void* const* d_in, const int* in_sizes, int n_in,
                              void* d_out, int out_size, void* d_ws, size_t ws_size,
                              hipStream_t stream)
{
    const float* x       = (const float*)d_in[0];
    const float* w_qkv   = (const float*)d_in[1];
    const float* w_o     = (const float*)d_in[2];
    const float* qc1_w   = (const float*)d_in[3];
    const float* qc1_b   = (const float*)d_in[4];
    const float* qc2_w   = (const float*)d_in[5];
    const float* qc2_b   = (const float*)d_in[6];
    const float* kc1_w   = (const float*)d_in[7];
    const float* kc1_b   = (const float*)d_in[8];
    const float* kc2_w   = (const float*)d_in[9];
    const float* kc2_b   = (const float*)d_in[10];
    const float* key_temp = (const float*)d_in[11];

    // --- workspace layout (aliased by lifetime) ---
    char* wsb = (char*)d_ws;
    float* qkv = (float*)wsb;                 wsb += (size_t)BS * QKVN * 4;
    float* qc2 = qkv;
    float* kc2 = (float*)((char*)qkv + (size_t)BS * LATENT * 4);
    unsigned short* pq  = (unsigned short*)wsb;  wsb += (size_t)NB * SP * LATENT * 2;
    unsigned short* pk  = (unsigned short*)wsb;  wsb += (size_t)NB * SP * KVD * 2;
    float* qmean = (float*)wsb;  wsb += (size_t)BS * HD * 4;
    float* kmean = (float*)wsb;  wsb += (size_t)BS * HD * 4;
    unsigned short* qTb  = (unsigned short*)wsb;  wsb += (size_t)BS * LATENT * 2;
    unsigned short* kTb  = (unsigned short*)wsb;  wsb += (size_t)BS * KVD * 2;
    unsigned short* vRow = (unsigned short*)wsb;  wsb += (size_t)BS * KVD * 2;
    unsigned short* vTb  = (unsigned short*)wsb;  wsb += (size_t)BS * KVD * 2;
    unsigned short* xb   = (unsigned short*)wsb;  wsb += (size_t)BS * DIMX * 2;
    unsigned short* attnb  = xb;
    unsigned short* qc2wr  = (unsigned short*)((char*)xb + (size_t)BS * LATENT * 2);
    unsigned short* kc2wr  = (unsigned short*)((char*)qc2wr + (size_t)LATENT * LATENT * 3 * 2);
    unsigned short* wqkvb = (unsigned short*)wsb;  wsb += (size_t)QKVN * DIMX * 2;
    unsigned short* wob   = wqkvb;
    // attention split-K partials alias the (dead-by-then) qkv/pq/pk region:
    unsigned short* pnum = (unsigned short*)d_ws;                       // 33.55 MB
    float* pden = (float*)((char*)d_ws + (size_t)33554432);             // +1.05 MB

    float* outp = (float*)d_out;

    cast_f2b<<<dim3(BS * DIMX / 4 / 256), 256, 0, stream>>>(x, xb, BS * DIMX / 4);
    cast_f2b<<<dim3(QKVN * DIMX / 4 / 256), 256, 0, stream>>>(w_qkv, wqkvb, QKVN * DIMX / 4);
    gemm_bf16<0><<<dim3(QKVN / 128, BS / 128), 256, 0, stream>>>(xb, wqkvb, nullptr, qkv, BS, QKVN, DIMX, 0);
    cast_f2b<<<dim3(DIMX * LATENT / 4 / 256), 256, 0, stream>>>(w_o, wob, DIMX * LATENT / 4);
    w3reorder<<<dim3((LATENT * LATENT * 3 + 255) / 256), 256, 0, stream>>>(qc2_w, qc2wr, LATENT, LATENT);
    w3reorder<<<dim3((KVD * KVD * 3 + 255) / 256), 256, 0, stream>>>(kc2_w, kc2wr, KVD, KVD);
    zero_pad<<<dim3(16), 256, 0, stream>>>(pq, pk);
    meanv_kernel<<<dim3(BS), 64, 0, stream>>>(qkv, qmean, kmean, vRow);
    vtrans<<<dim3(SEQ / 64, NB * NKV), 256, 0, stream>>>(vRow, vTb);
    conv1_grouped<<<dim3(SEQ / 64, NB, NH),  256, 0, stream>>>(qkv, 0,      qc1_w, qc1_b, pq, LATENT);
    conv1_grouped<<<dim3(SEQ / 64, NB, NKV), 256, 0, stream>>>(qkv, LATENT, kc1_w, kc1_b, pk, KVD);
    gemm_bf16<1><<<dim3(LATENT / 128, BS / 128), 256, 0, stream>>>(pq, qc2wr, qc2_b, qc2, BS, LATENT, LATENT * 3, LATENT);
    gemm_bf16<1><<<dim3(KVD / 128,    BS / 128), 256, 0, stream>>>(pk, kc2wr, kc2_b, kc2, BS, KVD,    KVD * 3,    KVD);
    qk_final<<<dim3(BS, NH + NKV), 64, 0, stream>>>(qc2, kc2, qmean, kmean, key_temp, qTb, kTb);
    attn_mfma<<<dim3(64, NB * NH), 256, 0, stream>>>(qTb, kTb, vTb, pnum, pden);
    attn_reduce<<<dim3(2048), 256, 0, stream>>>(pnum, pden, attnb);
    gemm_bf16<0><<<dim3(DIMX / 128, BS / 128), 256, 0, stream>>>(attnb, wob, nullptr, outp, BS, DIMX, LATENT, 0);
}

// Round 8
// 457.231 us; speedup vs baseline: 1.0842x; 1.0677x over previous
//
#include <hip/hip_runtime.h>
#include <hip/hip_bf16.h>
#include <cstddef>

#define NB 2
#define SEQ 2048
#define DIMX 4096
#define NH 16
#define NKV 4
#define HD 64
#define LATENT 1024
#define KVD 256
#define QKVN 1536
#define BS (NB*SEQ)
#define SP (SEQ+2)   // padded token rows per batch for conv2 input

typedef __attribute__((ext_vector_type(8))) short short8v;   // 8 bf16 = 4 VGPR
typedef __attribute__((ext_vector_type(4))) float f32x4;
typedef __attribute__((ext_vector_type(4))) unsigned short ushort4v;
typedef __attribute__((ext_vector_type(4))) unsigned int uint4v;

static __device__ __forceinline__ unsigned short f2bf(float f) {
    union { float f; unsigned u; } v; v.f = f;
    unsigned r = v.u + 0x7fffu + ((v.u >> 16) & 1u);
    return (unsigned short)(r >> 16);
}

static __device__ __forceinline__ unsigned cvt_pk_bf16(float lo, float hi) {
    unsigned r;
    asm("v_cvt_pk_bf16_f32 %0, %1, %2" : "=v"(r) : "v"(lo), "v"(hi));
    return r;
}

static __device__ __forceinline__ void gload_lds16(const unsigned short* g, unsigned short* l) {
    __builtin_amdgcn_global_load_lds((const __attribute__((address_space(1))) void*)g,
                                     (__attribute__((address_space(3))) void*)l, 16, 0, 0);
}

// ---------------- fp32 -> bf16 cast (vectorized x4) ----------------
__global__ __launch_bounds__(256)
void cast_f2b(const float* __restrict__ in, unsigned short* __restrict__ out, int n4)
{
    const int i = blockIdx.x * 256 + threadIdx.x;
    if (i < n4) {
        const float4 v = *reinterpret_cast<const float4*>(in + (size_t)i * 4);
        ushort4v o = {f2bf(v.x), f2bf(v.y), f2bf(v.z), f2bf(v.w)};
        *reinterpret_cast<ushort4v*>(out + (size_t)i * 4) = o;
    }
}

// ---------------- conv2 weight reorder: wr[o][j*I+c] = w[o][c][j], fp32->bf16 ----------------
__global__ __launch_bounds__(256)
void w3reorder(const float* __restrict__ w, unsigned short* __restrict__ wr, int O, int I)
{
    const int idx = blockIdx.x * 256 + threadIdx.x;
    if (idx < O * I * 3) {
        const int o = idx / (I * 3), rem = idx % (I * 3);
        const int j = rem / I, c = rem % I;
        wr[idx] = f2bf(w[(size_t)o * I * 3 + c * 3 + j]);
    }
}

// ---------------- zero the 2 pad rows per batch of the conv2 input buffers ----------------
__global__ __launch_bounds__(256)
void zero_pad(unsigned short* __restrict__ pq, unsigned short* __restrict__ pk)
{
    const int t = blockIdx.x * 256 + threadIdx.x;
    if (t < 2 * 2 * LATENT) {
        const int b = t / (2 * LATENT), r = (t % (2 * LATENT)) / LATENT, c = t % LATENT;
        pq[((size_t)b * SP + r) * LATENT + c] = 0;
    }
    if (t < 2 * 2 * KVD) {
        const int b = t / (2 * KVD), r = (t % (2 * KVD)) / KVD, c = t % KVD;
        pk[((size_t)b * SP + r) * KVD + c] = 0;
    }
}

// ---------------- bf16 MFMA GEMM: C[M][N] = A[M][K] @ W[N][K]^T (+bias), fp32 out ----------------
template<int CONV>
__global__ __launch_bounds__(256)
void gemm_bf16(const unsigned short* __restrict__ A, const unsigned short* __restrict__ W,
               const float* __restrict__ bias, float* __restrict__ C,
               int M, int N, int K, int Cch)
{
    __shared__ unsigned short Abuf[2][128 * 32];
    __shared__ unsigned short Bbuf[2][128 * 32];
    const int n0 = blockIdx.x * 128, m0 = blockIdx.y * 128;
    const int tid = threadIdx.x;
    const int wave = tid >> 6, lane = tid & 63;
    const int lg = lane >> 4, lr = lane & 15;
    const int wm = (wave & 1) * 64, wn = (wave >> 1) * 64;
    const int sr = wave * 32 + (lane >> 2);
    const int sc = (lane & 3) * 8;
    const int bb = m0 / SEQ, s0 = m0 % SEQ;

    const int NT = K / 32;
    f32x4 acc[4][4];
    #pragma unroll
    for (int i = 0; i < 4; i++)
        #pragma unroll
        for (int j = 0; j < 4; j++) acc[i][j] = (f32x4){0.f, 0.f, 0.f, 0.f};

    auto stage = [&](int buf, int kt) {
        const int k0 = kt * 32;
        const unsigned short* ga0;
        if (!CONV) {
            ga0 = A + (size_t)(m0 + sr) * K + k0 + sc;
        } else {
            const int j = k0 / Cch, c0 = k0 - j * Cch;
            ga0 = A + (size_t)(bb * SP + s0 + j + sr) * Cch + c0 + sc;
        }
        const unsigned short* gb0 = W + (size_t)(n0 + sr) * K + k0 + sc;
        const size_t astep = (size_t)16 * (CONV ? Cch : K);
        #pragma unroll
        for (int i = 0; i < 2; i++) {
            gload_lds16(ga0 + i * astep, &Abuf[buf][(wave * 2 + i) * 512]);
            gload_lds16(gb0 + (size_t)i * 16 * K, &Bbuf[buf][(wave * 2 + i) * 512]);
        }
    };

    stage(0, 0);
    __syncthreads();
    int cur = 0;
    for (int kt = 0; kt < NT; ++kt) {
        if (kt + 1 < NT) stage(cur ^ 1, kt + 1);
        short8v af[4], bf[4];
        #pragma unroll
        for (int mi = 0; mi < 4; mi++)
            af[mi] = *reinterpret_cast<const short8v*>(&Abuf[cur][(wm + mi * 16 + lr) * 32 + lg * 8]);
        #pragma unroll
        for (int ni = 0; ni < 4; ni++)
            bf[ni] = *reinterpret_cast<const short8v*>(&Bbuf[cur][(wn + ni * 16 + lr) * 32 + lg * 8]);
        #pragma unroll
        for (int mi = 0; mi < 4; mi++)
            #pragma unroll
            for (int ni = 0; ni < 4; ni++)
                acc[mi][ni] = __builtin_amdgcn_mfma_f32_16x16x32_bf16(af[mi], bf[ni], acc[mi][ni], 0, 0, 0);
        __syncthreads();
        cur ^= 1;
    }

    #pragma unroll
    for (int ni = 0; ni < 4; ni++) {
        const int col = n0 + wn + ni * 16 + lr;
        const float bv = bias ? bias[col] : 0.f;
        #pragma unroll
        for (int mi = 0; mi < 4; mi++)
            #pragma unroll
            for (int r = 0; r < 4; r++)
                C[(size_t)(m0 + wm + mi * 16 + lg * 4 + r) * N + col] = acc[mi][ni][r] + bv;
    }
}

// ---------------- grouped causal conv1 -> bf16 padded [b][SP][CH] (rows 0,1 zero) ----------------
__global__ __launch_bounds__(256)
void conv1_grouped(const float* __restrict__ qkv, int coloff,
                   const float* __restrict__ w, const float* __restrict__ bias,
                   unsigned short* __restrict__ out, int CH)
{
    const int t0 = blockIdx.x * 64;
    const int b  = blockIdx.y;
    const int g  = blockIdx.z;
    __shared__ float xs[66][64];
    for (int idx = threadIdx.x; idx < 66 * 64; idx += 256) {
        const int i = idx >> 6, ic = idx & 63;
        const int tt = t0 + i - 2;
        xs[i][ic] = (tt >= 0) ? qkv[(size_t)(b * SEQ + tt) * QKVN + coloff + g * 64 + ic] : 0.f;
    }
    __syncthreads();
    const int oc = threadIdx.x & 63;
    const int ibase = (threadIdx.x >> 6) * 16;
    float acc[16];
    const float bv = bias[g * 64 + oc];
    #pragma unroll
    for (int i = 0; i < 16; i++) acc[i] = bv;
    const float* wp = w + (size_t)(g * 64 + oc) * 192;
    for (int ic = 0; ic < 64; ic++) {
        const float w0 = wp[ic * 3 + 0], w1 = wp[ic * 3 + 1], w2 = wp[ic * 3 + 2];
        float xv[18];
        #pragma unroll
        for (int r = 0; r < 18; r++) xv[r] = xs[ibase + r][ic];
        #pragma unroll
        for (int i = 0; i < 16; i++) acc[i] += w0 * xv[i] + w1 * xv[i + 1] + w2 * xv[i + 2];
    }
    #pragma unroll
    for (int i = 0; i < 16; i++)
        out[((size_t)b * SP + 2 + t0 + ibase + i) * CH + g * 64 + oc] = f2bf(acc[i]);
}

// ---------------- head means + shifted-v build (row-major bf16) ----------------
__global__ __launch_bounds__(64)
void meanv_kernel(const float* __restrict__ qkv, float* __restrict__ qmean,
                  float* __restrict__ kmean, unsigned short* __restrict__ vRow)
{
    const int t = blockIdx.x, d = threadIdx.x;
    const int b = t >> 11, s = t & (SEQ - 1);
    const float* row = qkv + (size_t)t * QKVN;
    float qs = 0.f;
    #pragma unroll
    for (int h = 0; h < NH; h++) qs += row[h * 64 + d];
    qmean[t * 64 + d] = qs * (1.f / NH);
    float ks = 0.f;
    #pragma unroll
    for (int h = 0; h < NKV; h++) ks += row[LATENT + h * 64 + d];
    kmean[t * 64 + d] = ks * (1.f / NKV);
    #pragma unroll
    for (int g = 0; g < NKV; g++) {
        const int c = g * 64 + d;
        float v;
        if (c < 128) v = row[LATENT + KVD + c];
        else         v = (s > 0) ? qkv[(size_t)(t - 1) * QKVN + LATENT + KVD + 128 + (c - 128)] : 0.f;
        vRow[((size_t)(b * NKV + g) * SEQ + s) * 64 + d] = f2bf(v);
    }
}

// ---------------- V transpose to d-major: vTb[bg][d][S] ----------------
__global__ __launch_bounds__(256)
void vtrans(const unsigned short* __restrict__ vRow, unsigned short* __restrict__ vTb)
{
    const int s0 = blockIdx.x * 64;
    const int bg = blockIdx.y;
    __shared__ unsigned short t[64][72];
    const int tid = threadIdx.x;
    {
        const int r = tid >> 2, c0 = (tid & 3) * 16;
        const unsigned short* p = vRow + ((size_t)bg * SEQ + s0 + r) * 64 + c0;
        const short8v a = *reinterpret_cast<const short8v*>(p);
        const short8v bv = *reinterpret_cast<const short8v*>(p + 8);
        #pragma unroll
        for (int j = 0; j < 8; j++) { t[r][c0 + j] = (unsigned short)a[j]; t[r][c0 + 8 + j] = (unsigned short)bv[j]; }
    }
    __syncthreads();
    {
        const int d = tid >> 2, ss = (tid & 3) * 16;
        short8v o0, o1;
        #pragma unroll
        for (int j = 0; j < 8; j++) { o0[j] = (short)t[ss + j][d]; o1[j] = (short)t[ss + 8 + j][d]; }
        unsigned short* op = vTb + ((size_t)bg * 64 + d) * SEQ + s0 + ss;
        *reinterpret_cast<short8v*>(op) = o0;
        *reinterpret_cast<short8v*>(op + 8) = o1;
    }
}

// ---------------- +0.5*mean, l2norm, rope -> bf16 (B,H,S,D) ----------------
__global__ __launch_bounds__(64)
void qk_final(const float* __restrict__ qc2, const float* __restrict__ kc2,
              const float* __restrict__ qmean, const float* __restrict__ kmean,
              const float* __restrict__ key_temp,
              unsigned short* __restrict__ qTb, unsigned short* __restrict__ kTb)
{
    const int t = blockIdx.x, hh = blockIdx.y, d = threadIdx.x;
    const int b = t >> 11, s = t & (SEQ - 1);
    float val;
    if (hh < NH) val = qc2[(size_t)t * LATENT + hh * 64 + d]        + 0.5f * kmean[t * 64 + d];
    else         val = kc2[(size_t)t * KVD    + (hh - NH) * 64 + d] + 0.5f * qmean[t * 64 + d];
    float ss = val * val;
    #pragma unroll
    for (int off = 32; off >= 1; off >>= 1) ss += __shfl_xor(ss, off);
    const float n = sqrtf(ss);
    val = val / fmaxf(n, 1e-12f);
    if (hh >= NH) val *= key_temp[0];
    const int i = d >> 1;
    const float inv = powf(10000.f, -(float)(2 * i) * (1.f / HD));
    const float ang = (float)s * inv;
    const float cv = cosf(ang), sv = sinf(ang);
    const float partner = __shfl_xor(val, 1);
    const float x1 = (d & 1) ? partner : val;
    const float x2 = (d & 1) ? val : partner;
    const float o = (d & 1) ? (x1 * sv + x2 * cv) : (x1 * cv - x2 * sv);
    if (hh < NH) qTb[((size_t)(b * NH + hh) * SEQ + s) * 64 + d] = f2bf(o);
    else         kTb[((size_t)(b * NKV + (hh - NH)) * SEQ + s) * 64 + d] = f2bf(o);
}

// ---------------- MFMA causal GQA attention: 4-wave block shares K/V via LDS ----------------
// Block = 4 waves = 4 consecutive q-tiles of one (b,h). Block walks key tiles once,
// double-buffer staging K+V (fragment-linear layout, conflict-free contiguous ds_read_b128).
// Swapped QK^T (mfma(K,Q)) keeps P in-lane; cvt_pk+shfl builds PV A-frag (R7-verified).
__global__ __launch_bounds__(256)
void attn_mfma(const unsigned short* __restrict__ qTb, const unsigned short* __restrict__ kTb,
               const unsigned short* __restrict__ vTb, unsigned short* __restrict__ attn_out)
{
    // bijective XCD swizzle: 512 blocks, 64 contiguous per XCD (= 4 bh's worth)
    const int wg = blockIdx.x;
    const int swz = (wg & 7) * 64 + (wg >> 3);
    const int bh = swz >> 4;
    const int blk = 15 - (swz & 15);         // longest-first within bh
    const int b = bh >> 4, h = bh & 15, g = h >> 2;
    const int tid = threadIdx.x;
    const int wave = tid >> 6, lane = tid & 63;
    const int lg = lane >> 4, lr = lane & 15;
    const int qt = blk * 4 + wave;           // this wave's q-tile
    const int q0 = qt * 32;
    const int ctot = (blk + 1) * 4;          // key tiles the block walks

    // K chunks 0..3 = (kt*2+dc), V chunks 4..7 = dt; each chunk 64 lanes x 16B
    __shared__ __align__(16) unsigned short SB[2][8][512];

    short8v qf[2][2];
    const unsigned short* qbase = qTb + ((size_t)(b * NH + h) * SEQ + q0) * 64;
    #pragma unroll
    for (int mf = 0; mf < 2; mf++)
        #pragma unroll
        for (int dc = 0; dc < 2; dc++)
            qf[mf][dc] = *reinterpret_cast<const short8v*>(qbase + (size_t)(mf * 16 + lr) * 64 + dc * 32 + lg * 8);

    f32x4 acc[2][4];
    float lsum[2] = {0.f, 0.f};
    #pragma unroll
    for (int mf = 0; mf < 2; mf++)
        #pragma unroll
        for (int dt = 0; dt < 4; dt++) acc[mf][dt] = (f32x4){0.f, 0.f, 0.f, 0.f};

    const unsigned short* kbase = kTb + (size_t)(b * NKV + g) * SEQ * 64;
    const unsigned short* vbase = vTb + (size_t)(b * NKV + g) * 64 * SEQ;
    const float EC = 0.125f * 1.44269504f;
    const int src01 = ((lg & 1) << 5) + lr;
    const int src23 = src01 + 16;
    const bool hi = (lg >= 2);

    // wave w stages chunks 2w, 2w+1 (K for w<2, V for w>=2)
    auto stage = [&](int buf, int c) {
        const int k0 = c * 32;
        #pragma unroll
        for (int i = 0; i < 2; i++) {
            const int ch = wave * 2 + i;
            const unsigned short* src;
            if (ch < 4) src = kbase + (size_t)(k0 + (ch >> 1) * 16 + lr) * 64 + (ch & 1) * 32 + lg * 8;
            else        src = vbase + (size_t)((ch - 4) * 16 + lr) * SEQ + k0 + lg * 8;
            gload_lds16(src, &SB[buf][ch][lane * 8]);
        }
    };

    stage(0, 0);
    __syncthreads();
    int cur = 0;
    for (int c = 0; c < ctot; ++c) {
        if (c + 1 < ctot) stage(cur ^ 1, c + 1);
        if (c <= qt) {
            const int k0 = c * 32;
            short8v kf[2][2], vf[4];
            #pragma unroll
            for (int kt = 0; kt < 2; kt++)
                #pragma unroll
                for (int dc = 0; dc < 2; dc++)
                    kf[kt][dc] = *reinterpret_cast<const short8v*>(&SB[cur][kt * 2 + dc][lane * 8]);
            #pragma unroll
            for (int dt = 0; dt < 4; dt++)
                vf[dt] = *reinterpret_cast<const short8v*>(&SB[cur][4 + dt][lane * 8]);

            const bool diag = (c == qt);
            #pragma unroll
            for (int mf = 0; mf < 2; mf++) {
                f32x4 z0 = (f32x4){0.f, 0.f, 0.f, 0.f}, z1 = (f32x4){0.f, 0.f, 0.f, 0.f};
                z0 = __builtin_amdgcn_mfma_f32_16x16x32_bf16(kf[0][0], qf[mf][0], z0, 0, 0, 0);
                z0 = __builtin_amdgcn_mfma_f32_16x16x32_bf16(kf[0][1], qf[mf][1], z0, 0, 0, 0);
                z1 = __builtin_amdgcn_mfma_f32_16x16x32_bf16(kf[1][0], qf[mf][0], z1, 0, 0, 0);
                z1 = __builtin_amdgcn_mfma_f32_16x16x32_bf16(kf[1][1], qf[mf][1], z1, 0, 0, 0);
                float p0[4], p1[4];
                #pragma unroll
                for (int r = 0; r < 4; r++) {
                    p0[r] = exp2f(z0[r] * EC);
                    p1[r] = exp2f(z1[r] * EC);
                }
                if (diag) {
                    const int q = q0 + mf * 16 + lr;
                    #pragma unroll
                    for (int r = 0; r < 4; r++) {
                        if (k0 + 4 * lg + r > q)      p0[r] = 0.f;
                        if (k0 + 16 + 4 * lg + r > q) p1[r] = 0.f;
                    }
                }
                lsum[mf] += (p0[0] + p0[1]) + (p0[2] + p0[3]) + (p1[0] + p1[1]) + (p1[2] + p1[3]);
                const unsigned W00 = cvt_pk_bf16(p0[0], p0[1]);
                const unsigned W01 = cvt_pk_bf16(p0[2], p0[3]);
                const unsigned W10 = cvt_pk_bf16(p1[0], p1[1]);
                const unsigned W11 = cvt_pk_bf16(p1[2], p1[3]);
                const unsigned a0 = __shfl(W00, src01), b0 = __shfl(W10, src01);
                const unsigned a1 = __shfl(W01, src01), b1 = __shfl(W11, src01);
                const unsigned a2 = __shfl(W00, src23), b2 = __shfl(W10, src23);
                const unsigned a3 = __shfl(W01, src23), b3 = __shfl(W11, src23);
                uint4v pw;
                pw.x = hi ? b0 : a0;
                pw.y = hi ? b1 : a1;
                pw.z = hi ? b2 : a2;
                pw.w = hi ? b3 : a3;
                const short8v pa = __builtin_bit_cast(short8v, pw);
                #pragma unroll
                for (int dt = 0; dt < 4; dt++)
                    acc[mf][dt] = __builtin_amdgcn_mfma_f32_16x16x32_bf16(pa, vf[dt], acc[mf][dt], 0, 0, 0);
            }
        }
        __syncthreads();
        cur ^= 1;
    }

    // full denominators: sum over the 4 lane-groups -> every lane holds den for q = q0+mf*16+lr
    float den[2];
    #pragma unroll
    for (int mf = 0; mf < 2; mf++) {
        float s = lsum[mf];
        s += __shfl_xor(s, 16); s += __shfl_xor(s, 32);
        den[mf] = s;
    }

    // normalize + store: acc row q_local = 4*lg+r -> fetch its den from lane (4*lg+r)
    #pragma unroll
    for (int mf = 0; mf < 2; mf++) {
        float dinv[4];
        #pragma unroll
        for (int r = 0; r < 4; r++) dinv[r] = 1.f / __shfl(den[mf], 4 * lg + r);
        #pragma unroll
        for (int dt = 0; dt < 4; dt++)
            #pragma unroll
            for (int r = 0; r < 4; r++) {
                const int q = q0 + mf * 16 + 4 * lg + r;
                attn_out[(size_t)(b * SEQ + q) * LATENT + h * 64 + dt * 16 + lr] = f2bf(acc[mf][dt][r] * dinv[r]);
            }
    }
}

extern "C" void kernel_launch(void* const* d_in, const int* in_sizes, int n_in,
                              void* d_out, int out_size, void* d_ws, size_t ws_size,
                              hipStream_t stream)
{
    const float* x       = (const float*)d_in[0];
    const float* w_qkv   = (const float*)d_in[1];
    const float* w_o     = (const float*)d_in[2];
    const float* qc1_w   = (const float*)d_in[3];
    const float* qc1_b   = (const float*)d_in[4];
    const float* qc2_w   = (const float*)d_in[5];
    const float* qc2_b   = (const float*)d_in[6];
    const float* kc1_w   = (const float*)d_in[7];
    const float* kc1_b   = (const float*)d_in[8];
    const float* kc2_w   = (const float*)d_in[9];
    const float* kc2_b   = (const float*)d_in[10];
    const float* key_temp = (const float*)d_in[11];

    // --- workspace layout (aliased by lifetime) ---
    char* wsb = (char*)d_ws;
    float* qkv = (float*)wsb;                 wsb += (size_t)BS * QKVN * 4;
    float* qc2 = qkv;
    float* kc2 = (float*)((char*)qkv + (size_t)BS * LATENT * 4);
    unsigned short* pq  = (unsigned short*)wsb;  wsb += (size_t)NB * SP * LATENT * 2;
    unsigned short* pk  = (unsigned short*)wsb;  wsb += (size_t)NB * SP * KVD * 2;
    float* qmean = (float*)wsb;  wsb += (size_t)BS * HD * 4;
    float* kmean = (float*)wsb;  wsb += (size_t)BS * HD * 4;
    unsigned short* qTb  = (unsigned short*)wsb;  wsb += (size_t)BS * LATENT * 2;
    unsigned short* kTb  = (unsigned short*)wsb;  wsb += (size_t)BS * KVD * 2;
    unsigned short* vRow = (unsigned short*)wsb;  wsb += (size_t)BS * KVD * 2;
    unsigned short* vTb  = (unsigned short*)wsb;  wsb += (size_t)BS * KVD * 2;
    unsigned short* xb   = (unsigned short*)wsb;  wsb += (size_t)BS * DIMX * 2;
    unsigned short* attnb  = xb;
    unsigned short* qc2wr  = (unsigned short*)((char*)xb + (size_t)BS * LATENT * 2);
    unsigned short* kc2wr  = (unsigned short*)((char*)qc2wr + (size_t)LATENT * LATENT * 3 * 2);
    unsigned short* wqkvb = (unsigned short*)wsb;  wsb += (size_t)QKVN * DIMX * 2;
    unsigned short* wob   = wqkvb;

    float* outp = (float*)d_out;

    cast_f2b<<<dim3(BS * DIMX / 4 / 256), 256, 0, stream>>>(x, xb, BS * DIMX / 4);
    cast_f2b<<<dim3(QKVN * DIMX / 4 / 256), 256, 0, stream>>>(w_qkv, wqkvb, QKVN * DIMX / 4);
    gemm_bf16<0><<<dim3(QKVN / 128, BS / 128), 256, 0, stream>>>(xb, wqkvb, nullptr, qkv, BS, QKVN, DIMX, 0);
    cast_f2b<<<dim3(DIMX * LATENT / 4 / 256), 256, 0, stream>>>(w_o, wob, DIMX * LATENT / 4);
    w3reorder<<<dim3((LATENT * LATENT * 3 + 255) / 256), 256, 0, stream>>>(qc2_w, qc2wr, LATENT, LATENT);
    w3reorder<<<dim3((KVD * KVD * 3 + 255) / 256), 256, 0, stream>>>(kc2_w, kc2wr, KVD, KVD);
    zero_pad<<<dim3(16), 256, 0, stream>>>(pq, pk);
    meanv_kernel<<<dim3(BS), 64, 0, stream>>>(qkv, qmean, kmean, vRow);
    vtrans<<<dim3(SEQ / 64, NB * NKV), 256, 0, stream>>>(vRow, vTb);
    conv1_grouped<<<dim3(SEQ / 64, NB, NH),  256, 0, stream>>>(qkv, 0,      qc1_w, qc1_b, pq, LATENT);
    conv1_grouped<<<dim3(SEQ / 64, NB, NKV), 256, 0, stream>>>(qkv, LATENT, kc1_w, kc1_b, pk, KVD);
    gemm_bf16<1><<<dim3(LATENT / 128, BS / 128), 256, 0, stream>>>(pq, qc2wr, qc2_b, qc2, BS, LATENT, LATENT * 3, LATENT);
    gemm_bf16<1><<<dim3(KVD / 128,    BS / 128), 256, 0, stream>>>(pk, kc2wr, kc2_b, kc2, BS, KVD,    KVD * 3,    KVD);
    qk_final<<<dim3(BS, NH + NKV), 64, 0, stream>>>(qc2, kc2, qmean, kmean, key_temp, qTb, kTb);
    attn_mfma<<<dim3(512), 256, 0, stream>>>(qTb, kTb, vTb, attnb);
    gemm_bf16<0><<<dim3(DIMX / 128, BS / 128), 256, 0, stream>>>(attnb, wob, nullptr, outp, BS, DIMX, LATENT, 0);
}

// Round 9
// 424.222 us; speedup vs baseline: 1.1686x; 1.0778x over previous
//
#include <hip/hip_runtime.h>
#include <hip/hip_bf16.h>
#include <cstddef>

#define NB 2
#define SEQ 2048
#define DIMX 4096
#define NH 16
#define NKV 4
#define HD 64
#define LATENT 1024
#define KVD 256
#define QKVN 1536
#define BS (NB*SEQ)
#define SP (SEQ+2)   // padded token rows per batch for conv2 input

typedef __attribute__((ext_vector_type(8))) short short8v;   // 8 bf16 = 4 VGPR
typedef __attribute__((ext_vector_type(4))) float f32x4;
typedef __attribute__((ext_vector_type(4))) unsigned short ushort4v;
typedef __attribute__((ext_vector_type(4))) unsigned int uint4v;

static __device__ __forceinline__ unsigned short f2bf(float f) {
    union { float f; unsigned u; } v; v.f = f;
    unsigned r = v.u + 0x7fffu + ((v.u >> 16) & 1u);
    return (unsigned short)(r >> 16);
}

static __device__ __forceinline__ unsigned cvt_pk_bf16(float lo, float hi) {
    unsigned r;
    asm("v_cvt_pk_bf16_f32 %0, %1, %2" : "=v"(r) : "v"(lo), "v"(hi));
    return r;
}

static __device__ __forceinline__ void gload_lds16(const unsigned short* g, unsigned short* l) {
    __builtin_amdgcn_global_load_lds((const __attribute__((address_space(1))) void*)g,
                                     (__attribute__((address_space(3))) void*)l, 16, 0, 0);
}

// ---------------- fp32 -> bf16 cast (vectorized x4) ----------------
__global__ __launch_bounds__(256)
void cast_f2b(const float* __restrict__ in, unsigned short* __restrict__ out, int n4)
{
    const int i = blockIdx.x * 256 + threadIdx.x;
    if (i < n4) {
        const float4 v = *reinterpret_cast<const float4*>(in + (size_t)i * 4);
        ushort4v o = {f2bf(v.x), f2bf(v.y), f2bf(v.z), f2bf(v.w)};
        *reinterpret_cast<ushort4v*>(out + (size_t)i * 4) = o;
    }
}

// ---------------- conv2 weight reorder: wr[o][j*I+c] = w[o][c][j], fp32->bf16 ----------------
__global__ __launch_bounds__(256)
void w3reorder(const float* __restrict__ w, unsigned short* __restrict__ wr, int O, int I)
{
    const int idx = blockIdx.x * 256 + threadIdx.x;
    if (idx < O * I * 3) {
        const int o = idx / (I * 3), rem = idx % (I * 3);
        const int j = rem / I, c = rem % I;
        wr[idx] = f2bf(w[(size_t)o * I * 3 + c * 3 + j]);
    }
}

// ---------------- zero the 2 pad rows per batch of the conv2 input buffers ----------------
__global__ __launch_bounds__(256)
void zero_pad(unsigned short* __restrict__ pq, unsigned short* __restrict__ pk)
{
    const int t = blockIdx.x * 256 + threadIdx.x;
    if (t < 2 * 2 * LATENT) {
        const int b = t / (2 * LATENT), r = (t % (2 * LATENT)) / LATENT, c = t % LATENT;
        pq[((size_t)b * SP + r) * LATENT + c] = 0;
    }
    if (t < 2 * 2 * KVD) {
        const int b = t / (2 * KVD), r = (t % (2 * KVD)) / KVD, c = t % KVD;
        pk[((size_t)b * SP + r) * KVD + c] = 0;
    }
}

// ---------------- merge split-K partials: out = p0 + p1 (+ bias) ----------------
__global__ __launch_bounds__(256)
void add2(const float* __restrict__ p0, const float* __restrict__ p1,
          const float* __restrict__ bias, float* __restrict__ out, int n4, int ncols)
{
    const int i = blockIdx.x * 256 + threadIdx.x;
    if (i < n4) {
        const float4 a = *reinterpret_cast<const float4*>(p0 + (size_t)i * 4);
        const float4 b = *reinterpret_cast<const float4*>(p1 + (size_t)i * 4);
        float4 o = make_float4(a.x + b.x, a.y + b.y, a.z + b.z, a.w + b.w);
        if (bias != nullptr) {
            const int col = (i * 4) % ncols;
            o.x += bias[col]; o.y += bias[col + 1]; o.z += bias[col + 2]; o.w += bias[col + 3];
        }
        *reinterpret_cast<float4*>(out + (size_t)i * 4) = o;
    }
}

// ---------------- bf16 MFMA GEMM: C[M][N] = A[M][K] @ W[N][K]^T, fp32 out ----------------
// 128x128 tile, BK=32, 2-phase double-buffered global_load_lds staging.
// Split-K: grid.z slices of klen; slice z covers K range [z*klen, (z+1)*klen) and
// writes C + z*pstride. XCD-aware block swizzle (gridDim.x*gridDim.y % 8 == 0).
// CONV=1: A is padded conv input [b][SP][Cch] bf16; virtual K = j*Cch + c.
template<int CONV>
__global__ __launch_bounds__(256)
void gemm_bf16(const unsigned short* __restrict__ A, const unsigned short* __restrict__ W,
               const float* __restrict__ bias, float* __restrict__ C,
               int M, int N, int K, int Cch, int klen, size_t pstride)
{
    __shared__ unsigned short Abuf[2][128 * 32];
    __shared__ unsigned short Bbuf[2][128 * 32];
    const int gx = gridDim.x;
    const int nwg = gx * gridDim.y;
    const int lin = blockIdx.y * gx + blockIdx.x;
    const int swz = (lin & 7) * (nwg >> 3) + (lin >> 3);
    const int n0 = (swz % gx) * 128, m0 = (swz / gx) * 128;
    const int koff = blockIdx.z * klen;
    C += (size_t)blockIdx.z * pstride;
    const int tid = threadIdx.x;
    const int wave = tid >> 6, lane = tid & 63;
    const int lg = lane >> 4, lr = lane & 15;
    const int wm = (wave & 1) * 64, wn = (wave >> 1) * 64;
    const int sr = wave * 32 + (lane >> 2);
    const int sc = (lane & 3) * 8;
    const int bb = m0 / SEQ, s0 = m0 % SEQ;

    const int NT = klen / 32;
    f32x4 acc[4][4];
    #pragma unroll
    for (int i = 0; i < 4; i++)
        #pragma unroll
        for (int j = 0; j < 4; j++) acc[i][j] = (f32x4){0.f, 0.f, 0.f, 0.f};

    auto stage = [&](int buf, int kt) {
        const int k0 = koff + kt * 32;
        const unsigned short* ga0;
        if (!CONV) {
            ga0 = A + (size_t)(m0 + sr) * K + k0 + sc;
        } else {
            const int j = k0 / Cch, c0 = k0 - j * Cch;
            ga0 = A + (size_t)(bb * SP + s0 + j + sr) * Cch + c0 + sc;
        }
        const unsigned short* gb0 = W + (size_t)(n0 + sr) * K + k0 + sc;
        const size_t astep = (size_t)16 * (CONV ? Cch : K);
        #pragma unroll
        for (int i = 0; i < 2; i++) {
            gload_lds16(ga0 + i * astep, &Abuf[buf][(wave * 2 + i) * 512]);
            gload_lds16(gb0 + (size_t)i * 16 * K, &Bbuf[buf][(wave * 2 + i) * 512]);
        }
    };

    stage(0, 0);
    __syncthreads();
    int cur = 0;
    for (int kt = 0; kt < NT; ++kt) {
        if (kt + 1 < NT) stage(cur ^ 1, kt + 1);
        short8v af[4], bf[4];
        #pragma unroll
        for (int mi = 0; mi < 4; mi++)
            af[mi] = *reinterpret_cast<const short8v*>(&Abuf[cur][(wm + mi * 16 + lr) * 32 + lg * 8]);
        #pragma unroll
        for (int ni = 0; ni < 4; ni++)
            bf[ni] = *reinterpret_cast<const short8v*>(&Bbuf[cur][(wn + ni * 16 + lr) * 32 + lg * 8]);
        #pragma unroll
        for (int mi = 0; mi < 4; mi++)
            #pragma unroll
            for (int ni = 0; ni < 4; ni++)
                acc[mi][ni] = __builtin_amdgcn_mfma_f32_16x16x32_bf16(af[mi], bf[ni], acc[mi][ni], 0, 0, 0);
        __syncthreads();
        cur ^= 1;
    }

    #pragma unroll
    for (int ni = 0; ni < 4; ni++) {
        const int col = n0 + wn + ni * 16 + lr;
        const float bv = bias ? bias[col] : 0.f;
        #pragma unroll
        for (int mi = 0; mi < 4; mi++)
            #pragma unroll
            for (int r = 0; r < 4; r++)
                C[(size_t)(m0 + wm + mi * 16 + lg * 4 + r) * N + col] = acc[mi][ni][r] + bv;
    }
}

// ---------------- grouped causal conv1 -> bf16 padded [b][SP][CH] (rows 0,1 zero) ----------------
__global__ __launch_bounds__(256)
void conv1_grouped(const float* __restrict__ qkv, int coloff,
                   const float* __restrict__ w, const float* __restrict__ bias,
                   unsigned short* __restrict__ out, int CH)
{
    const int t0 = blockIdx.x * 64;
    const int b  = blockIdx.y;
    const int g  = blockIdx.z;
    __shared__ float xs[66][64];
    for (int idx = threadIdx.x; idx < 66 * 64; idx += 256) {
        const int i = idx >> 6, ic = idx & 63;
        const int tt = t0 + i - 2;
        xs[i][ic] = (tt >= 0) ? qkv[(size_t)(b * SEQ + tt) * QKVN + coloff + g * 64 + ic] : 0.f;
    }
    __syncthreads();
    const int oc = threadIdx.x & 63;
    const int ibase = (threadIdx.x >> 6) * 16;
    float acc[16];
    const float bv = bias[g * 64 + oc];
    #pragma unroll
    for (int i = 0; i < 16; i++) acc[i] = bv;
    const float* wp = w + (size_t)(g * 64 + oc) * 192;
    for (int ic = 0; ic < 64; ic++) {
        const float w0 = wp[ic * 3 + 0], w1 = wp[ic * 3 + 1], w2 = wp[ic * 3 + 2];
        float xv[18];
        #pragma unroll
        for (int r = 0; r < 18; r++) xv[r] = xs[ibase + r][ic];
        #pragma unroll
        for (int i = 0; i < 16; i++) acc[i] += w0 * xv[i] + w1 * xv[i + 1] + w2 * xv[i + 2];
    }
    #pragma unroll
    for (int i = 0; i < 16; i++)
        out[((size_t)b * SP + 2 + t0 + ibase + i) * CH + g * 64 + oc] = f2bf(acc[i]);
}

// ---------------- head means + shifted-v build (row-major bf16) ----------------
__global__ __launch_bounds__(64)
void meanv_kernel(const float* __restrict__ qkv, float* __restrict__ qmean,
                  float* __restrict__ kmean, unsigned short* __restrict__ vRow)
{
    const int t = blockIdx.x, d = threadIdx.x;
    const int b = t >> 11, s = t & (SEQ - 1);
    const float* row = qkv + (size_t)t * QKVN;
    float qs = 0.f;
    #pragma unroll
    for (int h = 0; h < NH; h++) qs += row[h * 64 + d];
    qmean[t * 64 + d] = qs * (1.f / NH);
    float ks = 0.f;
    #pragma unroll
    for (int h = 0; h < NKV; h++) ks += row[LATENT + h * 64 + d];
    kmean[t * 64 + d] = ks * (1.f / NKV);
    #pragma unroll
    for (int g = 0; g < NKV; g++) {
        const int c = g * 64 + d;
        float v;
        if (c < 128) v = row[LATENT + KVD + c];
        else         v = (s > 0) ? qkv[(size_t)(t - 1) * QKVN + LATENT + KVD + 128 + (c - 128)] : 0.f;
        vRow[((size_t)(b * NKV + g) * SEQ + s) * 64 + d] = f2bf(v);
    }
}

// ---------------- V transpose to d-major: vTb[bg][d][S] ----------------
__global__ __launch_bounds__(256)
void vtrans(const unsigned short* __restrict__ vRow, unsigned short* __restrict__ vTb)
{
    const int s0 = blockIdx.x * 64;
    const int bg = blockIdx.y;
    __shared__ unsigned short t[64][72];
    const int tid = threadIdx.x;
    {
        const int r = tid >> 2, c0 = (tid & 3) * 16;
        const unsigned short* p = vRow + ((size_t)bg * SEQ + s0 + r) * 64 + c0;
        const short8v a = *reinterpret_cast<const short8v*>(p);
        const short8v bv = *reinterpret_cast<const short8v*>(p + 8);
        #pragma unroll
        for (int j = 0; j < 8; j++) { t[r][c0 + j] = (unsigned short)a[j]; t[r][c0 + 8 + j] = (unsigned short)bv[j]; }
    }
    __syncthreads();
    {
        const int d = tid >> 2, ss = (tid & 3) * 16;
        short8v o0, o1;
        #pragma unroll
        for (int j = 0; j < 8; j++) { o0[j] = (short)t[ss + j][d]; o1[j] = (short)t[ss + 8 + j][d]; }
        unsigned short* op = vTb + ((size_t)bg * 64 + d) * SEQ + s0 + ss;
        *reinterpret_cast<short8v*>(op) = o0;
        *reinterpret_cast<short8v*>(op + 8) = o1;
    }
}

// ---------------- +0.5*mean, l2norm, rope -> bf16 (B,H,S,D) ----------------
__global__ __launch_bounds__(64)
void qk_final(const float* __restrict__ qc2, const float* __restrict__ kc2,
              const float* __restrict__ qmean, const float* __restrict__ kmean,
              const float* __restrict__ key_temp,
              unsigned short* __restrict__ qTb, unsigned short* __restrict__ kTb)
{
    const int t = blockIdx.x, hh = blockIdx.y, d = threadIdx.x;
    const int b = t >> 11, s = t & (SEQ - 1);
    float val;
    if (hh < NH) val = qc2[(size_t)t * LATENT + hh * 64 + d]        + 0.5f * kmean[t * 64 + d];
    else         val = kc2[(size_t)t * KVD    + (hh - NH) * 64 + d] + 0.5f * qmean[t * 64 + d];
    float ss = val * val;
    #pragma unroll
    for (int off = 32; off >= 1; off >>= 1) ss += __shfl_xor(ss, off);
    const float n = sqrtf(ss);
    val = val / fmaxf(n, 1e-12f);
    if (hh >= NH) val *= key_temp[0];
    const int i = d >> 1;
    const float inv = powf(10000.f, -(float)(2 * i) * (1.f / HD));
    const float ang = (float)s * inv;
    const float cv = cosf(ang), sv = sinf(ang);
    const float partner = __shfl_xor(val, 1);
    const float x1 = (d & 1) ? partner : val;
    const float x2 = (d & 1) ? val : partner;
    const float o = (d & 1) ? (x1 * sv + x2 * cv) : (x1 * cv - x2 * sv);
    if (hh < NH) qTb[((size_t)(b * NH + hh) * SEQ + s) * 64 + d] = f2bf(o);
    else         kTb[((size_t)(b * NKV + (hh - NH)) * SEQ + s) * 64 + d] = f2bf(o);
}

// ---------------- MFMA causal GQA attention: 4-wave block shares K/V via LDS ----------------
__global__ __launch_bounds__(256)
void attn_mfma(const unsigned short* __restrict__ qTb, const unsigned short* __restrict__ kTb,
               const unsigned short* __restrict__ vTb, unsigned short* __restrict__ attn_out)
{
    const int wg = blockIdx.x;
    const int swz = (wg & 7) * 64 + (wg >> 3);
    const int bh = swz >> 4;
    const int blk = 15 - (swz & 15);         // longest-first within bh
    const int b = bh >> 4, h = bh & 15, g = h >> 2;
    const int tid = threadIdx.x;
    const int wave = tid >> 6, lane = tid & 63;
    const int lg = lane >> 4, lr = lane & 15;
    const int qt = blk * 4 + wave;
    const int q0 = qt * 32;
    const int ctot = (blk + 1) * 4;

    __shared__ __align__(16) unsigned short SB[2][8][512];

    short8v qf[2][2];
    const unsigned short* qbase = qTb + ((size_t)(b * NH + h) * SEQ + q0) * 64;
    #pragma unroll
    for (int mf = 0; mf < 2; mf++)
        #pragma unroll
        for (int dc = 0; dc < 2; dc++)
            qf[mf][dc] = *reinterpret_cast<const short8v*>(qbase + (size_t)(mf * 16 + lr) * 64 + dc * 32 + lg * 8);

    f32x4 acc[2][4];
    float lsum[2] = {0.f, 0.f};
    #pragma unroll
    for (int mf = 0; mf < 2; mf++)
        #pragma unroll
        for (int dt = 0; dt < 4; dt++) acc[mf][dt] = (f32x4){0.f, 0.f, 0.f, 0.f};

    const unsigned short* kbase = kTb + (size_t)(b * NKV + g) * SEQ * 64;
    const unsigned short* vbase = vTb + (size_t)(b * NKV + g) * 64 * SEQ;
    const float EC = 0.125f * 1.44269504f;
    const int src01 = ((lg & 1) << 5) + lr;
    const int src23 = src01 + 16;
    const bool hi = (lg >= 2);

    auto stage = [&](int buf, int c) {
        const int k0 = c * 32;
        #pragma unroll
        for (int i = 0; i < 2; i++) {
            const int ch = wave * 2 + i;
            const unsigned short* src;
            if (ch < 4) src = kbase + (size_t)(k0 + (ch >> 1) * 16 + lr) * 64 + (ch & 1) * 32 + lg * 8;
            else        src = vbase + (size_t)((ch - 4) * 16 + lr) * SEQ + k0 + lg * 8;
            gload_lds16(src, &SB[buf][ch][lane * 8]);
        }
    };

    stage(0, 0);
    __syncthreads();
    int cur = 0;
    for (int c = 0; c < ctot; ++c) {
        if (c + 1 < ctot) stage(cur ^ 1, c + 1);
        if (c <= qt) {
            const int k0 = c * 32;
            short8v kf[2][2], vf[4];
            #pragma unroll
            for (int kt = 0; kt < 2; kt++)
                #pragma unroll
                for (int dc = 0; dc < 2; dc++)
                    kf[kt][dc] = *reinterpret_cast<const short8v*>(&SB[cur][kt * 2 + dc][lane * 8]);
            #pragma unroll
            for (int dt = 0; dt < 4; dt++)
                vf[dt] = *reinterpret_cast<const short8v*>(&SB[cur][4 + dt][lane * 8]);

            const bool diag = (c == qt);
            #pragma unroll
            for (int mf = 0; mf < 2; mf++) {
                f32x4 z0 = (f32x4){0.f, 0.f, 0.f, 0.f}, z1 = (f32x4){0.f, 0.f, 0.f, 0.f};
                z0 = __builtin_amdgcn_mfma_f32_16x16x32_bf16(kf[0][0], qf[mf][0], z0, 0, 0, 0);
                z0 = __builtin_amdgcn_mfma_f32_16x16x32_bf16(kf[0][1], qf[mf][1], z0, 0, 0, 0);
                z1 = __builtin_amdgcn_mfma_f32_16x16x32_bf16(kf[1][0], qf[mf][0], z1, 0, 0, 0);
                z1 = __builtin_amdgcn_mfma_f32_16x16x32_bf16(kf[1][1], qf[mf][1], z1, 0, 0, 0);
                float p0[4], p1[4];
                #pragma unroll
                for (int r = 0; r < 4; r++) {
                    p0[r] = exp2f(z0[r] * EC);
                    p1[r] = exp2f(z1[r] * EC);
                }
                if (diag) {
                    const int q = q0 + mf * 16 + lr;
                    #pragma unroll
                    for (int r = 0; r < 4; r++) {
                        if (k0 + 4 * lg + r > q)      p0[r] = 0.f;
                        if (k0 + 16 + 4 * lg + r > q) p1[r] = 0.f;
                    }
                }
                lsum[mf] += (p0[0] + p0[1]) + (p0[2] + p0[3]) + (p1[0] + p1[1]) + (p1[2] + p1[3]);
                const unsigned W00 = cvt_pk_bf16(p0[0], p0[1]);
                const unsigned W01 = cvt_pk_bf16(p0[2], p0[3]);
                const unsigned W10 = cvt_pk_bf16(p1[0], p1[1]);
                const unsigned W11 = cvt_pk_bf16(p1[2], p1[3]);
                const unsigned a0 = __shfl(W00, src01), b0 = __shfl(W10, src01);
                const unsigned a1 = __shfl(W01, src01), b1 = __shfl(W11, src01);
                const unsigned a2 = __shfl(W00, src23), b2 = __shfl(W10, src23);
                const unsigned a3 = __shfl(W01, src23), b3 = __shfl(W11, src23);
                uint4v pw;
                pw.x = hi ? b0 : a0;
                pw.y = hi ? b1 : a1;
                pw.z = hi ? b2 : a2;
                pw.w = hi ? b3 : a3;
                const short8v pa = __builtin_bit_cast(short8v, pw);
                #pragma unroll
                for (int dt = 0; dt < 4; dt++)
                    acc[mf][dt] = __builtin_amdgcn_mfma_f32_16x16x32_bf16(pa, vf[dt], acc[mf][dt], 0, 0, 0);
            }
        }
        __syncthreads();
        cur ^= 1;
    }

    float den[2];
    #pragma unroll
    for (int mf = 0; mf < 2; mf++) {
        float s = lsum[mf];
        s += __shfl_xor(s, 16); s += __shfl_xor(s, 32);
        den[mf] = s;
    }

    #pragma unroll
    for (int mf = 0; mf < 2; mf++) {
        float dinv[4];
        #pragma unroll
        for (int r = 0; r < 4; r++) dinv[r] = 1.f / __shfl(den[mf], 4 * lg + r);
        #pragma unroll
        for (int dt = 0; dt < 4; dt++)
            #pragma unroll
            for (int r = 0; r < 4; r++) {
                const int q = q0 + mf * 16 + 4 * lg + r;
                attn_out[(size_t)(b * SEQ + q) * LATENT + h * 64 + dt * 16 + lr] = f2bf(acc[mf][dt][r] * dinv[r]);
            }
    }
}

extern "C" void kernel_launch(void* const* d_in, const int* in_sizes, int n_in,
                              void* d_out, int out_size, void* d_ws, size_t ws_size,
                              hipStream_t stream)
{
    const float* x       = (const float*)d_in[0];
    const float* w_qkv   = (const float*)d_in[1];
    const float* w_o     = (const float*)d_in[2];
    const float* qc1_w   = (const float*)d_in[3];
    const float* qc1_b   = (const float*)d_in[4];
    const float* qc2_w   = (const float*)d_in[5];
    const float* qc2_b   = (const float*)d_in[6];
    const float* kc1_w   = (const float*)d_in[7];
    const float* kc1_b   = (const float*)d_in[8];
    const float* kc2_w   = (const float*)d_in[9];
    const float* kc2_b   = (const float*)d_in[10];
    const float* key_temp = (const float*)d_in[11];

    // --- workspace layout (aliased by lifetime; offsets in bytes noted) ---
    char* wsb = (char*)d_ws;
    float* qkv = (float*)wsb;                 wsb += (size_t)BS * QKVN * 4;     // [0, 25165824)
    float* qc2 = qkv;                                                            // alias (qkv dead after conv1)
    float* kc2 = (float*)((char*)qkv + (size_t)BS * LATENT * 4);                 // [16777216, 20971520)
    unsigned short* pq  = (unsigned short*)wsb;  wsb += (size_t)NB * SP * LATENT * 2;
    unsigned short* pk  = (unsigned short*)wsb;  wsb += (size_t)NB * SP * KVD * 2;
    float* qmean = (float*)wsb;  wsb += (size_t)BS * HD * 4;
    float* kmean = (float*)wsb;  wsb += (size_t)BS * HD * 4;
    unsigned short* qTb  = (unsigned short*)wsb;  wsb += (size_t)BS * LATENT * 2;
    unsigned short* kTb  = (unsigned short*)wsb;  wsb += (size_t)BS * KVD * 2;
    unsigned short* vRow = (unsigned short*)wsb;  wsb += (size_t)BS * KVD * 2;
    unsigned short* vTb  = (unsigned short*)wsb;  wsb += (size_t)BS * KVD * 2;   // ends 52439040
    unsigned short* xb   = (unsigned short*)wsb;  wsb += (size_t)BS * DIMX * 2;  // [52439040, 85993472)
    unsigned short* attnb  = xb;                                                 // [52439040, 60827648)
    unsigned short* qc2wr  = (unsigned short*)((char*)xb + (size_t)BS * LATENT * 2);        // ..67119104
    unsigned short* kc2wr  = (unsigned short*)((char*)qc2wr + (size_t)LATENT * LATENT * 3 * 2); // ..67512320
    unsigned short* wqkvb = (unsigned short*)wsb;  wsb += (size_t)QKVN * DIMX * 2;  // [85993472, 98576384)
    unsigned short* wob   = wqkvb;

    // split-K partial placement (regions dead at their GEMM's position in stream order):
    // qkv partials: p0 = qkv itself, p1 = qkv + M*N  (covers [0, 50331648) -- pre-meanv region)
    const size_t QKV_PS = (size_t)BS * QKVN;
    // conv2 partials: p1 in the free xb tail [67512320, 85993472)
    float* c2p1 = (float*)((char*)d_ws + 67512320);
    const size_t QC2_PS = (size_t)(c2p1 - qc2);   // float offset of p1 from qc2
    const size_t KC2_PS = (size_t)(c2p1 - kc2);

    float* outp = (float*)d_out;

    // 1. casts for qkv GEMM
    cast_f2b<<<dim3(BS * DIMX / 4 / 256), 256, 0, stream>>>(x, xb, BS * DIMX / 4);
    cast_f2b<<<dim3(QKVN * DIMX / 4 / 256), 256, 0, stream>>>(w_qkv, wqkvb, QKVN * DIMX / 4);
    // 2. qkv projection, split-K=2 (768 blocks) + merge
    gemm_bf16<0><<<dim3(QKVN / 128, BS / 128, 2), 256, 0, stream>>>(xb, wqkvb, nullptr, qkv, BS, QKVN, DIMX, 0, DIMX / 2, QKV_PS);
    add2<<<dim3(BS * QKVN / 4 / 256), 256, 0, stream>>>(qkv, qkv + QKV_PS, nullptr, qkv, BS * QKVN / 4, 4);
    // 3. prep for later GEMMs (xb/wqkvb dead)
    cast_f2b<<<dim3(DIMX * LATENT / 4 / 256), 256, 0, stream>>>(w_o, wob, DIMX * LATENT / 4);
    w3reorder<<<dim3((LATENT * LATENT * 3 + 255) / 256), 256, 0, stream>>>(qc2_w, qc2wr, LATENT, LATENT);
    w3reorder<<<dim3((KVD * KVD * 3 + 255) / 256), 256, 0, stream>>>(kc2_w, kc2wr, KVD, KVD);
    // 4. means + shifted v (after qkv merge), V transpose, pads
    meanv_kernel<<<dim3(BS), 64, 0, stream>>>(qkv, qmean, kmean, vRow);
    vtrans<<<dim3(SEQ / 64, NB * NKV), 256, 0, stream>>>(vRow, vTb);
    zero_pad<<<dim3(16), 256, 0, stream>>>(pq, pk);
    // 5. grouped conv1 -> padded bf16
    conv1_grouped<<<dim3(SEQ / 64, NB, NH),  256, 0, stream>>>(qkv, 0,      qc1_w, qc1_b, pq, LATENT);
    conv1_grouped<<<dim3(SEQ / 64, NB, NKV), 256, 0, stream>>>(qkv, LATENT, kc1_w, kc1_b, pk, KVD);
    // 6. conv2 as split-K bf16 GEMMs + merges (bias applied in merge)
    gemm_bf16<1><<<dim3(LATENT / 128, BS / 128, 2), 256, 0, stream>>>(pq, qc2wr, nullptr, qc2, BS, LATENT, LATENT * 3, LATENT, LATENT * 3 / 2, QC2_PS);
    add2<<<dim3(BS * LATENT / 4 / 256), 256, 0, stream>>>(qc2, qc2 + QC2_PS, qc2_b, qc2, BS * LATENT / 4, LATENT);
    gemm_bf16<1><<<dim3(KVD / 128, BS / 128, 2), 256, 0, stream>>>(pk, kc2wr, nullptr, kc2, BS, KVD, KVD * 3, KVD, KVD * 3 / 2, KC2_PS);
    add2<<<dim3(BS * KVD / 4 / 256), 256, 0, stream>>>(kc2, kc2 + KC2_PS, kc2_b, kc2, BS * KVD / 4, KVD);
    // 7. +0.5*mean, l2norm, rope
    qk_final<<<dim3(BS, NH + NKV), 64, 0, stream>>>(qc2, kc2, qmean, kmean, key_temp, qTb, kTb);
    // 8. attention
    attn_mfma<<<dim3(512), 256, 0, stream>>>(qTb, kTb, vTb, attnb);
    // 9. output projection (1024 blocks, 4/CU -- no split needed)
    gemm_bf16<0><<<dim3(DIMX / 128, BS / 128, 1), 256, 0, stream>>>(attnb, wob, nullptr, outp, BS, DIMX, LATENT, 0, LATENT, 0);
}

// Round 10
// 394.108 us; speedup vs baseline: 1.2579x; 1.0764x over previous
//
#include <hip/hip_runtime.h>
#include <hip/hip_bf16.h>
#include <cstddef>

#define NB 2
#define SEQ 2048
#define DIMX 4096
#define NH 16
#define NKV 4
#define HD 64
#define LATENT 1024
#define KVD 256
#define QKVN 1536
#define BS (NB*SEQ)
#define SP (SEQ+2)   // padded token rows per batch for conv2 input

typedef __attribute__((ext_vector_type(8))) short short8v;   // 8 bf16 = 4 VGPR
typedef __attribute__((ext_vector_type(4))) float f32x4;
typedef __attribute__((ext_vector_type(4))) unsigned short ushort4v;
typedef __attribute__((ext_vector_type(4))) unsigned int uint4v;

static __device__ __forceinline__ unsigned short f2bf(float f) {
    union { float f; unsigned u; } v; v.f = f;
    unsigned r = v.u + 0x7fffu + ((v.u >> 16) & 1u);
    return (unsigned short)(r >> 16);
}

static __device__ __forceinline__ unsigned cvt_pk_bf16(float lo, float hi) {
    unsigned r;
    asm("v_cvt_pk_bf16_f32 %0, %1, %2" : "=v"(r) : "v"(lo), "v"(hi));
    return r;
}

static __device__ __forceinline__ void gload_lds16(const unsigned short* g, unsigned short* l) {
    __builtin_amdgcn_global_load_lds((const __attribute__((address_space(1))) void*)g,
                                     (__attribute__((address_space(3))) void*)l, 16, 0, 0);
}

// ---------------- fp32 -> bf16 cast (vectorized x4) ----------------
__global__ __launch_bounds__(256)
void cast_f2b(const float* __restrict__ in, unsigned short* __restrict__ out, int n4)
{
    const int i = blockIdx.x * 256 + threadIdx.x;
    if (i < n4) {
        const float4 v = *reinterpret_cast<const float4*>(in + (size_t)i * 4);
        ushort4v o = {f2bf(v.x), f2bf(v.y), f2bf(v.z), f2bf(v.w)};
        *reinterpret_cast<ushort4v*>(out + (size_t)i * 4) = o;
    }
}

// ---------------- conv2 weight reorder: wr[o][j*I+c] = w[o][c][j], fp32->bf16 ----------------
__global__ __launch_bounds__(256)
void w3reorder(const float* __restrict__ w, unsigned short* __restrict__ wr, int O, int I)
{
    const int idx = blockIdx.x * 256 + threadIdx.x;
    if (idx < O * I * 3) {
        const int o = idx / (I * 3), rem = idx % (I * 3);
        const int j = rem / I, c = rem % I;
        wr[idx] = f2bf(w[(size_t)o * I * 3 + c * 3 + j]);
    }
}

// ---------------- zero the 2 pad rows per batch of the conv2 input buffers ----------------
__global__ __launch_bounds__(256)
void zero_pad(unsigned short* __restrict__ pq, unsigned short* __restrict__ pk)
{
    const int t = blockIdx.x * 256 + threadIdx.x;
    if (t < 2 * 2 * LATENT) {
        const int b = t / (2 * LATENT), r = (t % (2 * LATENT)) / LATENT, c = t % LATENT;
        pq[((size_t)b * SP + r) * LATENT + c] = 0;
    }
    if (t < 2 * 2 * KVD) {
        const int b = t / (2 * KVD), r = (t % (2 * KVD)) / KVD, c = t % KVD;
        pk[((size_t)b * SP + r) * KVD + c] = 0;
    }
}

// ---------------- merge split-K partials: out = p0 + p1 (+ bias) ----------------
__global__ __launch_bounds__(256)
void add2(const float* __restrict__ p0, const float* __restrict__ p1,
          const float* __restrict__ bias, float* __restrict__ out, int n4, int ncols)
{
    const int i = blockIdx.x * 256 + threadIdx.x;
    if (i < n4) {
        const float4 a = *reinterpret_cast<const float4*>(p0 + (size_t)i * 4);
        const float4 b = *reinterpret_cast<const float4*>(p1 + (size_t)i * 4);
        float4 o = make_float4(a.x + b.x, a.y + b.y, a.z + b.z, a.w + b.w);
        if (bias != nullptr) {
            const int col = (i * 4) % ncols;
            o.x += bias[col]; o.y += bias[col + 1]; o.z += bias[col + 2]; o.w += bias[col + 3];
        }
        *reinterpret_cast<float4*>(out + (size_t)i * 4) = o;
    }
}

// ---------------- bf16 MFMA GEMM: C[M][N] = A[M][K] @ W[N][K]^T, fp32 out ----------------
// 128x128 tile, BK=32, 2-phase double-buffered global_load_lds staging, split-K via grid.z.
template<int CONV>
__global__ __launch_bounds__(256)
void gemm_bf16(const unsigned short* __restrict__ A, const unsigned short* __restrict__ W,
               const float* __restrict__ bias, float* __restrict__ C,
               int M, int N, int K, int Cch, int klen, size_t pstride)
{
    __shared__ unsigned short Abuf[2][128 * 32];
    __shared__ unsigned short Bbuf[2][128 * 32];
    const int gx = gridDim.x;
    const int nwg = gx * gridDim.y;
    const int lin = blockIdx.y * gx + blockIdx.x;
    const int swz = (lin & 7) * (nwg >> 3) + (lin >> 3);
    const int n0 = (swz % gx) * 128, m0 = (swz / gx) * 128;
    const int koff = blockIdx.z * klen;
    C += (size_t)blockIdx.z * pstride;
    const int tid = threadIdx.x;
    const int wave = tid >> 6, lane = tid & 63;
    const int lg = lane >> 4, lr = lane & 15;
    const int wm = (wave & 1) * 64, wn = (wave >> 1) * 64;
    const int sr = wave * 32 + (lane >> 2);
    const int sc = (lane & 3) * 8;
    const int bb = m0 / SEQ, s0 = m0 % SEQ;

    const int NT = klen / 32;
    f32x4 acc[4][4];
    #pragma unroll
    for (int i = 0; i < 4; i++)
        #pragma unroll
        for (int j = 0; j < 4; j++) acc[i][j] = (f32x4){0.f, 0.f, 0.f, 0.f};

    auto stage = [&](int buf, int kt) {
        const int k0 = koff + kt * 32;
        const unsigned short* ga0;
        if (!CONV) {
            ga0 = A + (size_t)(m0 + sr) * K + k0 + sc;
        } else {
            const int j = k0 / Cch, c0 = k0 - j * Cch;
            ga0 = A + (size_t)(bb * SP + s0 + j + sr) * Cch + c0 + sc;
        }
        const unsigned short* gb0 = W + (size_t)(n0 + sr) * K + k0 + sc;
        const size_t astep = (size_t)16 * (CONV ? Cch : K);
        #pragma unroll
        for (int i = 0; i < 2; i++) {
            gload_lds16(ga0 + i * astep, &Abuf[buf][(wave * 2 + i) * 512]);
            gload_lds16(gb0 + (size_t)i * 16 * K, &Bbuf[buf][(wave * 2 + i) * 512]);
        }
    };

    stage(0, 0);
    __syncthreads();
    int cur = 0;
    for (int kt = 0; kt < NT; ++kt) {
        if (kt + 1 < NT) stage(cur ^ 1, kt + 1);
        short8v af[4], bf[4];
        #pragma unroll
        for (int mi = 0; mi < 4; mi++)
            af[mi] = *reinterpret_cast<const short8v*>(&Abuf[cur][(wm + mi * 16 + lr) * 32 + lg * 8]);
        #pragma unroll
        for (int ni = 0; ni < 4; ni++)
            bf[ni] = *reinterpret_cast<const short8v*>(&Bbuf[cur][(wn + ni * 16 + lr) * 32 + lg * 8]);
        #pragma unroll
        for (int mi = 0; mi < 4; mi++)
            #pragma unroll
            for (int ni = 0; ni < 4; ni++)
                acc[mi][ni] = __builtin_amdgcn_mfma_f32_16x16x32_bf16(af[mi], bf[ni], acc[mi][ni], 0, 0, 0);
        __syncthreads();
        cur ^= 1;
    }

    #pragma unroll
    for (int ni = 0; ni < 4; ni++) {
        const int col = n0 + wn + ni * 16 + lr;
        const float bv = bias ? bias[col] : 0.f;
        #pragma unroll
        for (int mi = 0; mi < 4; mi++)
            #pragma unroll
            for (int r = 0; r < 4; r++)
                C[(size_t)(m0 + wm + mi * 16 + lg * 4 + r) * N + col] = acc[mi][ni][r] + bv;
    }
}

// ---------------- grouped causal conv1 -> bf16 padded [b][SP][CH] (rows 0,1 zero) ----------------
__global__ __launch_bounds__(256)
void conv1_grouped(const float* __restrict__ qkv, int coloff,
                   const float* __restrict__ w, const float* __restrict__ bias,
                   unsigned short* __restrict__ out, int CH)
{
    const int t0 = blockIdx.x * 64;
    const int b  = blockIdx.y;
    const int g  = blockIdx.z;
    __shared__ float xs[66][64];
    for (int idx = threadIdx.x; idx < 66 * 64; idx += 256) {
        const int i = idx >> 6, ic = idx & 63;
        const int tt = t0 + i - 2;
        xs[i][ic] = (tt >= 0) ? qkv[(size_t)(b * SEQ + tt) * QKVN + coloff + g * 64 + ic] : 0.f;
    }
    __syncthreads();
    const int oc = threadIdx.x & 63;
    const int ibase = (threadIdx.x >> 6) * 16;
    float acc[16];
    const float bv = bias[g * 64 + oc];
    #pragma unroll
    for (int i = 0; i < 16; i++) acc[i] = bv;
    const float* wp = w + (size_t)(g * 64 + oc) * 192;
    for (int ic = 0; ic < 64; ic++) {
        const float w0 = wp[ic * 3 + 0], w1 = wp[ic * 3 + 1], w2 = wp[ic * 3 + 2];
        float xv[18];
        #pragma unroll
        for (int r = 0; r < 18; r++) xv[r] = xs[ibase + r][ic];
        #pragma unroll
        for (int i = 0; i < 16; i++) acc[i] += w0 * xv[i] + w1 * xv[i + 1] + w2 * xv[i + 2];
    }
    #pragma unroll
    for (int i = 0; i < 16; i++)
        out[((size_t)b * SP + 2 + t0 + ibase + i) * CH + g * 64 + oc] = f2bf(acc[i]);
}

// ---------------- head means + shifted-v build (row-major bf16) ----------------
__global__ __launch_bounds__(64)
void meanv_kernel(const float* __restrict__ qkv, float* __restrict__ qmean,
                  float* __restrict__ kmean, unsigned short* __restrict__ vRow)
{
    const int t = blockIdx.x, d = threadIdx.x;
    const int b = t >> 11, s = t & (SEQ - 1);
    const float* row = qkv + (size_t)t * QKVN;
    float qs = 0.f;
    #pragma unroll
    for (int h = 0; h < NH; h++) qs += row[h * 64 + d];
    qmean[t * 64 + d] = qs * (1.f / NH);
    float ks = 0.f;
    #pragma unroll
    for (int h = 0; h < NKV; h++) ks += row[LATENT + h * 64 + d];
    kmean[t * 64 + d] = ks * (1.f / NKV);
    #pragma unroll
    for (int g = 0; g < NKV; g++) {
        const int c = g * 64 + d;
        float v;
        if (c < 128) v = row[LATENT + KVD + c];
        else         v = (s > 0) ? qkv[(size_t)(t - 1) * QKVN + LATENT + KVD + 128 + (c - 128)] : 0.f;
        vRow[((size_t)(b * NKV + g) * SEQ + s) * 64 + d] = f2bf(v);
    }
}

// ---------------- V transpose to d-major: vTb[bg][d][S] ----------------
__global__ __launch_bounds__(256)
void vtrans(const unsigned short* __restrict__ vRow, unsigned short* __restrict__ vTb)
{
    const int s0 = blockIdx.x * 64;
    const int bg = blockIdx.y;
    __shared__ unsigned short t[64][72];
    const int tid = threadIdx.x;
    {
        const int r = tid >> 2, c0 = (tid & 3) * 16;
        const unsigned short* p = vRow + ((size_t)bg * SEQ + s0 + r) * 64 + c0;
        const short8v a = *reinterpret_cast<const short8v*>(p);
        const short8v bv = *reinterpret_cast<const short8v*>(p + 8);
        #pragma unroll
        for (int j = 0; j < 8; j++) { t[r][c0 + j] = (unsigned short)a[j]; t[r][c0 + 8 + j] = (unsigned short)bv[j]; }
    }
    __syncthreads();
    {
        const int d = tid >> 2, ss = (tid & 3) * 16;
        short8v o0, o1;
        #pragma unroll
        for (int j = 0; j < 8; j++) { o0[j] = (short)t[ss + j][d]; o1[j] = (short)t[ss + 8 + j][d]; }
        unsigned short* op = vTb + ((size_t)bg * 64 + d) * SEQ + s0 + ss;
        *reinterpret_cast<short8v*>(op) = o0;
        *reinterpret_cast<short8v*>(op + 8) = o1;
    }
}

// ---------------- fused conv2-partial merge + bias, +0.5*mean, l2norm, rope -> bf16 ----------------
__global__ __launch_bounds__(64)
void qk_final(const float* __restrict__ qc2a, const float* __restrict__ qc2b,
              const float* __restrict__ kc2a, const float* __restrict__ kc2b,
              const float* __restrict__ qbias, const float* __restrict__ kbias,
              const float* __restrict__ qmean, const float* __restrict__ kmean,
              const float* __restrict__ key_temp,
              unsigned short* __restrict__ qTb, unsigned short* __restrict__ kTb)
{
    const int t = blockIdx.x, hh = blockIdx.y, d = threadIdx.x;
    const int b = t >> 11, s = t & (SEQ - 1);
    float val;
    if (hh < NH) {
        const size_t off = (size_t)t * LATENT + hh * 64 + d;
        val = qc2a[off] + qc2b[off] + qbias[hh * 64 + d] + 0.5f * kmean[t * 64 + d];
    } else {
        const size_t off = (size_t)t * KVD + (hh - NH) * 64 + d;
        val = kc2a[off] + kc2b[off] + kbias[(hh - NH) * 64 + d] + 0.5f * qmean[t * 64 + d];
    }
    float ss = val * val;
    #pragma unroll
    for (int off = 32; off >= 1; off >>= 1) ss += __shfl_xor(ss, off);
    const float n = sqrtf(ss);
    val = val / fmaxf(n, 1e-12f);
    if (hh >= NH) val *= key_temp[0];
    const int i = d >> 1;
    const float inv = powf(10000.f, -(float)(2 * i) * (1.f / HD));
    const float ang = (float)s * inv;
    const float cv = cosf(ang), sv = sinf(ang);
    const float partner = __shfl_xor(val, 1);
    const float x1 = (d & 1) ? partner : val;
    const float x2 = (d & 1) ? val : partner;
    const float o = (d & 1) ? (x1 * sv + x2 * cv) : (x1 * cv - x2 * sv);
    if (hh < NH) qTb[((size_t)(b * NH + hh) * SEQ + s) * 64 + d] = f2bf(o);
    else         kTb[((size_t)(b * NKV + (hh - NH)) * SEQ + s) * 64 + d] = f2bf(o);
}

// ---------------- MFMA causal GQA attention: 4-wave block shares K/V via LDS ----------------
// Work-balanced dispatch: wg<256 carry long q-tile-groups (blk 8..15), wg>=256 the short
// complement (blk 0..7) with identical (xcd,i) structure -> CU pairs sum to ~17 tiles.
// Each XCD sees 4 bh = 1 (b,g) K/V set (L2-resident).
__global__ __launch_bounds__(256)
void attn_mfma(const unsigned short* __restrict__ qTb, const unsigned short* __restrict__ kTb,
               const unsigned short* __restrict__ vTb, unsigned short* __restrict__ attn_out)
{
    const int wg = blockIdx.x;
    int bh, blk;
    if (wg < 256) {
        const int xcd = wg & 7, i = wg >> 3;
        bh = (xcd << 2) | (i >> 3);
        blk = 15 - (i & 7);          // 8..15
    } else {
        const int u = wg - 256;
        const int xcd = u & 7, i = u >> 3;
        bh = (xcd << 2) | (i >> 3);
        blk = i & 7;                 // 0..7
    }
    const int b = bh >> 4, h = bh & 15, g = h >> 2;
    const int tid = threadIdx.x;
    const int wave = tid >> 6, lane = tid & 63;
    const int lg = lane >> 4, lr = lane & 15;
    const int qt = blk * 4 + wave;
    const int q0 = qt * 32;
    const int ctot = (blk + 1) * 4;

    __shared__ __align__(16) unsigned short SB[2][8][512];

    short8v qf[2][2];
    const unsigned short* qbase = qTb + ((size_t)(b * NH + h) * SEQ + q0) * 64;
    #pragma unroll
    for (int mf = 0; mf < 2; mf++)
        #pragma unroll
        for (int dc = 0; dc < 2; dc++)
            qf[mf][dc] = *reinterpret_cast<const short8v*>(qbase + (size_t)(mf * 16 + lr) * 64 + dc * 32 + lg * 8);

    f32x4 acc[2][4];
    float lsum[2] = {0.f, 0.f};
    #pragma unroll
    for (int mf = 0; mf < 2; mf++)
        #pragma unroll
        for (int dt = 0; dt < 4; dt++) acc[mf][dt] = (f32x4){0.f, 0.f, 0.f, 0.f};

    const unsigned short* kbase = kTb + (size_t)(b * NKV + g) * SEQ * 64;
    const unsigned short* vbase = vTb + (size_t)(b * NKV + g) * 64 * SEQ;
    const float EC = 0.125f * 1.44269504f;
    const int src01 = ((lg & 1) << 5) + lr;
    const int src23 = src01 + 16;
    const bool hi = (lg >= 2);

    auto stage = [&](int buf, int c) {
        const int k0 = c * 32;
        #pragma unroll
        for (int i = 0; i < 2; i++) {
            const int ch = wave * 2 + i;
            const unsigned short* src;
            if (ch < 4) src = kbase + (size_t)(k0 + (ch >> 1) * 16 + lr) * 64 + (ch & 1) * 32 + lg * 8;
            else        src = vbase + (size_t)((ch - 4) * 16 + lr) * SEQ + k0 + lg * 8;
            gload_lds16(src, &SB[buf][ch][lane * 8]);
        }
    };

    stage(0, 0);
    __syncthreads();
    int cur = 0;
    for (int c = 0; c < ctot; ++c) {
        if (c + 1 < ctot) stage(cur ^ 1, c + 1);
        if (c <= qt) {
            const int k0 = c * 32;
            short8v kf[2][2], vf[4];
            #pragma unroll
            for (int kt = 0; kt < 2; kt++)
                #pragma unroll
                for (int dc = 0; dc < 2; dc++)
                    kf[kt][dc] = *reinterpret_cast<const short8v*>(&SB[cur][kt * 2 + dc][lane * 8]);
            #pragma unroll
            for (int dt = 0; dt < 4; dt++)
                vf[dt] = *reinterpret_cast<const short8v*>(&SB[cur][4 + dt][lane * 8]);

            const bool diag = (c == qt);
            #pragma unroll
            for (int mf = 0; mf < 2; mf++) {
                f32x4 z0 = (f32x4){0.f, 0.f, 0.f, 0.f}, z1 = (f32x4){0.f, 0.f, 0.f, 0.f};
                z0 = __builtin_amdgcn_mfma_f32_16x16x32_bf16(kf[0][0], qf[mf][0], z0, 0, 0, 0);
                z0 = __builtin_amdgcn_mfma_f32_16x16x32_bf16(kf[0][1], qf[mf][1], z0, 0, 0, 0);
                z1 = __builtin_amdgcn_mfma_f32_16x16x32_bf16(kf[1][0], qf[mf][0], z1, 0, 0, 0);
                z1 = __builtin_amdgcn_mfma_f32_16x16x32_bf16(kf[1][1], qf[mf][1], z1, 0, 0, 0);
                float p0[4], p1[4];
                #pragma unroll
                for (int r = 0; r < 4; r++) {
                    p0[r] = exp2f(z0[r] * EC);
                    p1[r] = exp2f(z1[r] * EC);
                }
                if (diag) {
                    const int q = q0 + mf * 16 + lr;
                    #pragma unroll
                    for (int r = 0; r < 4; r++) {
                        if (k0 + 4 * lg + r > q)      p0[r] = 0.f;
                        if (k0 + 16 + 4 * lg + r > q) p1[r] = 0.f;
                    }
                }
                lsum[mf] += (p0[0] + p0[1]) + (p0[2] + p0[3]) + (p1[0] + p1[1]) + (p1[2] + p1[3]);
                const unsigned W00 = cvt_pk_bf16(p0[0], p0[1]);
                const unsigned W01 = cvt_pk_bf16(p0[2], p0[3]);
                const unsigned W10 = cvt_pk_bf16(p1[0], p1[1]);
                const unsigned W11 = cvt_pk_bf16(p1[2], p1[3]);
                const unsigned a0 = __shfl(W00, src01), b0 = __shfl(W10, src01);
                const unsigned a1 = __shfl(W01, src01), b1 = __shfl(W11, src01);
                const unsigned a2 = __shfl(W00, src23), b2 = __shfl(W10, src23);
                const unsigned a3 = __shfl(W01, src23), b3 = __shfl(W11, src23);
                uint4v pw;
                pw.x = hi ? b0 : a0;
                pw.y = hi ? b1 : a1;
                pw.z = hi ? b2 : a2;
                pw.w = hi ? b3 : a3;
                const short8v pa = __builtin_bit_cast(short8v, pw);
                #pragma unroll
                for (int dt = 0; dt < 4; dt++)
                    acc[mf][dt] = __builtin_amdgcn_mfma_f32_16x16x32_bf16(pa, vf[dt], acc[mf][dt], 0, 0, 0);
            }
        }
        __syncthreads();
        cur ^= 1;
    }

    float den[2];
    #pragma unroll
    for (int mf = 0; mf < 2; mf++) {
        float s = lsum[mf];
        s += __shfl_xor(s, 16); s += __shfl_xor(s, 32);
        den[mf] = s;
    }

    #pragma unroll
    for (int mf = 0; mf < 2; mf++) {
        float dinv[4];
        #pragma unroll
        for (int r = 0; r < 4; r++) dinv[r] = 1.f / __shfl(den[mf], 4 * lg + r);
        #pragma unroll
        for (int dt = 0; dt < 4; dt++)
            #pragma unroll
            for (int r = 0; r < 4; r++) {
                const int q = q0 + mf * 16 + 4 * lg + r;
                attn_out[(size_t)(b * SEQ + q) * LATENT + h * 64 + dt * 16 + lr] = f2bf(acc[mf][dt][r] * dinv[r]);
            }
    }
}

extern "C" void kernel_launch(void* const* d_in, const int* in_sizes, int n_in,
                              void* d_out, int out_size, void* d_ws, size_t ws_size,
                              hipStream_t stream)
{
    const float* x       = (const float*)d_in[0];
    const float* w_qkv   = (const float*)d_in[1];
    const float* w_o     = (const float*)d_in[2];
    const float* qc1_w   = (const float*)d_in[3];
    const float* qc1_b   = (const float*)d_in[4];
    const float* qc2_w   = (const float*)d_in[5];
    const float* qc2_b   = (const float*)d_in[6];
    const float* kc1_w   = (const float*)d_in[7];
    const float* kc1_b   = (const float*)d_in[8];
    const float* kc2_w   = (const float*)d_in[9];
    const float* kc2_b   = (const float*)d_in[10];
    const float* key_temp = (const float*)d_in[11];

    // --- workspace layout (aliased by lifetime; byte offsets noted) ---
    char* wsb = (char*)d_ws;
    float* qkv = (float*)wsb;                 wsb += (size_t)BS * QKVN * 4;     // [0, 25165824)
    float* qc2 = qkv;                                                            // alias (qkv dead after conv1)
    float* kc2 = (float*)((char*)qkv + (size_t)BS * LATENT * 4);                 // [16777216, 20971520)
    unsigned short* pq  = (unsigned short*)wsb;  wsb += (size_t)NB * SP * LATENT * 2;  // [25165824, ..)
    unsigned short* pk  = (unsigned short*)wsb;  wsb += (size_t)NB * SP * KVD * 2;
    float* qmean = (float*)wsb;  wsb += (size_t)BS * HD * 4;
    float* kmean = (float*)wsb;  wsb += (size_t)BS * HD * 4;
    unsigned short* qTb  = (unsigned short*)wsb;  wsb += (size_t)BS * LATENT * 2;
    unsigned short* kTb  = (unsigned short*)wsb;  wsb += (size_t)BS * KVD * 2;
    unsigned short* vRow = (unsigned short*)wsb;  wsb += (size_t)BS * KVD * 2;
    unsigned short* vTb  = (unsigned short*)wsb;  wsb += (size_t)BS * KVD * 2;   // ends 52439040
    unsigned short* xb   = (unsigned short*)wsb;  wsb += (size_t)BS * DIMX * 2;  // [52439040, 85993472)
    unsigned short* attnb  = xb;                                                 // [52439040, 60827648)
    unsigned short* qc2wr  = (unsigned short*)((char*)xb + (size_t)BS * LATENT * 2);        // ..67119104
    unsigned short* kc2wr  = (unsigned short*)((char*)qc2wr + (size_t)LATENT * LATENT * 3 * 2); // ..67512320
    unsigned short* wqkvb = (unsigned short*)wsb;  wsb += (size_t)QKVN * DIMX * 2;  // [85993472, 98576384)
    unsigned short* wob   = wqkvb;

    // split-K partial placement (regions dead in stream order at their GEMM's position):
    const size_t QKV_PS = (size_t)BS * QKVN;                      // qkv p1 at qkv+M*N (pre-meanv region)
    float* qc2p1 = (float*)((char*)d_ws + 67512320);              // xb tail (dead), 16.7MB
    float* kc2p1 = (float*)((char*)d_ws + (size_t)BS * QKVN * 4); // pq region (dead after conv2-q GEMM), 4.2MB
    const size_t QC2_PS = (size_t)(qc2p1 - qc2);
    const size_t KC2_PS = (size_t)(kc2p1 - kc2);

    float* outp = (float*)d_out;

    // 1. casts for qkv GEMM
    cast_f2b<<<dim3(BS * DIMX / 4 / 256), 256, 0, stream>>>(x, xb, BS * DIMX / 4);
    cast_f2b<<<dim3(QKVN * DIMX / 4 / 256), 256, 0, stream>>>(w_qkv, wqkvb, QKVN * DIMX / 4);
    // 2. qkv projection, split-K=2 (768 blocks) + merge
    gemm_bf16<0><<<dim3(QKVN / 128, BS / 128, 2), 256, 0, stream>>>(xb, wqkvb, nullptr, qkv, BS, QKVN, DIMX, 0, DIMX / 2, QKV_PS);
    add2<<<dim3(BS * QKVN / 4 / 256), 256, 0, stream>>>(qkv, qkv + QKV_PS, nullptr, qkv, BS * QKVN / 4, 4);
    // 3. prep for later GEMMs (xb/wqkvb dead)
    cast_f2b<<<dim3(DIMX * LATENT / 4 / 256), 256, 0, stream>>>(w_o, wob, DIMX * LATENT / 4);
    w3reorder<<<dim3((LATENT * LATENT * 3 + 255) / 256), 256, 0, stream>>>(qc2_w, qc2wr, LATENT, LATENT);
    w3reorder<<<dim3((KVD * KVD * 3 + 255) / 256), 256, 0, stream>>>(kc2_w, kc2wr, KVD, KVD);
    // 4. means + shifted v, V transpose, pads
    meanv_kernel<<<dim3(BS), 64, 0, stream>>>(qkv, qmean, kmean, vRow);
    vtrans<<<dim3(SEQ / 64, NB * NKV), 256, 0, stream>>>(vRow, vTb);
    zero_pad<<<dim3(16), 256, 0, stream>>>(pq, pk);
    // 5. grouped conv1 -> padded bf16
    conv1_grouped<<<dim3(SEQ / 64, NB, NH),  256, 0, stream>>>(qkv, 0,      qc1_w, qc1_b, pq, LATENT);
    conv1_grouped<<<dim3(SEQ / 64, NB, NKV), 256, 0, stream>>>(qkv, LATENT, kc1_w, kc1_b, pk, KVD);
    // 6. conv2 as split-K bf16 GEMMs; partials merged inside qk_final (no add2)
    gemm_bf16<1><<<dim3(LATENT / 128, BS / 128, 2), 256, 0, stream>>>(pq, qc2wr, nullptr, qc2, BS, LATENT, LATENT * 3, LATENT, LATENT * 3 / 2, QC2_PS);
    gemm_bf16<1><<<dim3(KVD / 128, BS / 128, 2), 256, 0, stream>>>(pk, kc2wr, nullptr, kc2, BS, KVD, KVD * 3, KVD, KVD * 3 / 2, KC2_PS);
    // 7. fused merge+bias, +0.5*mean, l2norm, rope
    qk_final<<<dim3(BS, NH + NKV), 64, 0, stream>>>(qc2, qc2p1, kc2, kc2p1, qc2_b, kc2_b,
                                                    qmean, kmean, key_temp, qTb, kTb);
    // 8. attention (work-balanced pairing)
    attn_mfma<<<dim3(512), 256, 0, stream>>>(qTb, kTb, vTb, attnb);
    // 9. output projection (1024 blocks, 4/CU)
    gemm_bf16<0><<<dim3(DIMX / 128, BS / 128, 1), 256, 0, stream>>>(attnb, wob, nullptr, outp, BS, DIMX, LATENT, 0, LATENT, 0);
}

// Round 11
// 382.331 us; speedup vs baseline: 1.2966x; 1.0308x over previous
//
#include <hip/hip_runtime.h>
#include <hip/hip_bf16.h>
#include <cstddef>

#define NB 2
#define SEQ 2048
#define DIMX 4096
#define NH 16
#define NKV 4
#define HD 64
#define LATENT 1024
#define KVD 256
#define QKVN 1536
#define BS (NB*SEQ)
#define SP (SEQ+2)   // padded token rows per batch for conv2 input

typedef __attribute__((ext_vector_type(8))) short short8v;   // 8 bf16 = 4 VGPR
typedef __attribute__((ext_vector_type(4))) float f32x4;
typedef __attribute__((ext_vector_type(4))) unsigned short ushort4v;
typedef __attribute__((ext_vector_type(4))) unsigned int uint4v;

static __device__ __forceinline__ unsigned short f2bf(float f) {
    union { float f; unsigned u; } v; v.f = f;
    unsigned r = v.u + 0x7fffu + ((v.u >> 16) & 1u);
    return (unsigned short)(r >> 16);
}

static __device__ __forceinline__ unsigned cvt_pk_bf16(float lo, float hi) {
    unsigned r;
    asm("v_cvt_pk_bf16_f32 %0, %1, %2" : "=v"(r) : "v"(lo), "v"(hi));
    return r;
}

static __device__ __forceinline__ void gload_lds16(const unsigned short* g, unsigned short* l) {
    __builtin_amdgcn_global_load_lds((const __attribute__((address_space(1))) void*)g,
                                     (__attribute__((address_space(3))) void*)l, 16, 0, 0);
}

// ---------------- fp32 -> bf16 cast (vectorized x4) ----------------
__global__ __launch_bounds__(256)
void cast_f2b(const float* __restrict__ in, unsigned short* __restrict__ out, int n4)
{
    const int i = blockIdx.x * 256 + threadIdx.x;
    if (i < n4) {
        const float4 v = *reinterpret_cast<const float4*>(in + (size_t)i * 4);
        ushort4v o = {f2bf(v.x), f2bf(v.y), f2bf(v.z), f2bf(v.w)};
        *reinterpret_cast<ushort4v*>(out + (size_t)i * 4) = o;
    }
}

// ---------------- conv2 weight reorder: wr[o][j*I+c] = w[o][c][j], fp32->bf16 ----------------
__global__ __launch_bounds__(256)
void w3reorder(const float* __restrict__ w, unsigned short* __restrict__ wr, int O, int I)
{
    const int idx = blockIdx.x * 256 + threadIdx.x;
    if (idx < O * I * 3) {
        const int o = idx / (I * 3), rem = idx % (I * 3);
        const int j = rem / I, c = rem % I;
        wr[idx] = f2bf(w[(size_t)o * I * 3 + c * 3 + j]);
    }
}

// ---------------- zero the 2 pad rows per batch of the conv2 input buffers ----------------
__global__ __launch_bounds__(256)
void zero_pad(unsigned short* __restrict__ pq, unsigned short* __restrict__ pk)
{
    const int t = blockIdx.x * 256 + threadIdx.x;
    if (t < 2 * 2 * LATENT) {
        const int b = t / (2 * LATENT), r = (t % (2 * LATENT)) / LATENT, c = t % LATENT;
        pq[((size_t)b * SP + r) * LATENT + c] = 0;
    }
    if (t < 2 * 2 * KVD) {
        const int b = t / (2 * KVD), r = (t % (2 * KVD)) / KVD, c = t % KVD;
        pk[((size_t)b * SP + r) * KVD + c] = 0;
    }
}

// ---------------- merge split-K partials: out = p0 + p1 (+ bias) ----------------
__global__ __launch_bounds__(256)
void add2(const float* __restrict__ p0, const float* __restrict__ p1,
          const float* __restrict__ bias, float* __restrict__ out, int n4, int ncols)
{
    const int i = blockIdx.x * 256 + threadIdx.x;
    if (i < n4) {
        const float4 a = *reinterpret_cast<const float4*>(p0 + (size_t)i * 4);
        const float4 b = *reinterpret_cast<const float4*>(p1 + (size_t)i * 4);
        float4 o = make_float4(a.x + b.x, a.y + b.y, a.z + b.z, a.w + b.w);
        if (bias != nullptr) {
            const int col = (i * 4) % ncols;
            o.x += bias[col]; o.y += bias[col + 1]; o.z += bias[col + 2]; o.w += bias[col + 3];
        }
        *reinterpret_cast<float4*>(out + (size_t)i * 4) = o;
    }
}

// ---------------- RoPE cos/sin table: tab[s][i] = {cos(s*inv_i), sin(s*inv_i)} ----------------
__global__ __launch_bounds__(256)
void rope_tab(float2* __restrict__ tab)
{
    const int idx = blockIdx.x * 256 + threadIdx.x;   // SEQ*32
    const int s = idx >> 5, i = idx & 31;
    const float inv = powf(10000.f, -(float)(2 * i) * (1.f / HD));
    const float ang = (float)s * inv;
    tab[idx] = make_float2(cosf(ang), sinf(ang));
}

// ---------------- bf16 MFMA GEMM: C[M][N] = A[M][K] @ W[N][K]^T, fp32 out ----------------
// 128x128 tile, BK=32, 2-phase double-buffered global_load_lds staging, split-K via grid.z.
template<int CONV>
__global__ __launch_bounds__(256)
void gemm_bf16(const unsigned short* __restrict__ A, const unsigned short* __restrict__ W,
               const float* __restrict__ bias, float* __restrict__ C,
               int M, int N, int K, int Cch, int klen, size_t pstride)
{
    __shared__ unsigned short Abuf[2][128 * 32];
    __shared__ unsigned short Bbuf[2][128 * 32];
    const int gx = gridDim.x;
    const int nwg = gx * gridDim.y;
    const int lin = blockIdx.y * gx + blockIdx.x;
    const int swz = (lin & 7) * (nwg >> 3) + (lin >> 3);
    const int n0 = (swz % gx) * 128, m0 = (swz / gx) * 128;
    const int koff = blockIdx.z * klen;
    C += (size_t)blockIdx.z * pstride;
    const int tid = threadIdx.x;
    const int wave = tid >> 6, lane = tid & 63;
    const int lg = lane >> 4, lr = lane & 15;
    const int wm = (wave & 1) * 64, wn = (wave >> 1) * 64;
    const int sr = wave * 32 + (lane >> 2);
    const int sc = (lane & 3) * 8;
    const int bb = m0 / SEQ, s0 = m0 % SEQ;

    const int NT = klen / 32;
    f32x4 acc[4][4];
    #pragma unroll
    for (int i = 0; i < 4; i++)
        #pragma unroll
        for (int j = 0; j < 4; j++) acc[i][j] = (f32x4){0.f, 0.f, 0.f, 0.f};

    auto stage = [&](int buf, int kt) {
        const int k0 = koff + kt * 32;
        const unsigned short* ga0;
        if (!CONV) {
            ga0 = A + (size_t)(m0 + sr) * K + k0 + sc;
        } else {
            const int j = k0 / Cch, c0 = k0 - j * Cch;
            ga0 = A + (size_t)(bb * SP + s0 + j + sr) * Cch + c0 + sc;
        }
        const unsigned short* gb0 = W + (size_t)(n0 + sr) * K + k0 + sc;
        const size_t astep = (size_t)16 * (CONV ? Cch : K);
        #pragma unroll
        for (int i = 0; i < 2; i++) {
            gload_lds16(ga0 + i * astep, &Abuf[buf][(wave * 2 + i) * 512]);
            gload_lds16(gb0 + (size_t)i * 16 * K, &Bbuf[buf][(wave * 2 + i) * 512]);
        }
    };

    stage(0, 0);
    __syncthreads();
    int cur = 0;
    for (int kt = 0; kt < NT; ++kt) {
        if (kt + 1 < NT) stage(cur ^ 1, kt + 1);
        short8v af[4], bf[4];
        #pragma unroll
        for (int mi = 0; mi < 4; mi++)
            af[mi] = *reinterpret_cast<const short8v*>(&Abuf[cur][(wm + mi * 16 + lr) * 32 + lg * 8]);
        #pragma unroll
        for (int ni = 0; ni < 4; ni++)
            bf[ni] = *reinterpret_cast<const short8v*>(&Bbuf[cur][(wn + ni * 16 + lr) * 32 + lg * 8]);
        #pragma unroll
        for (int mi = 0; mi < 4; mi++)
            #pragma unroll
            for (int ni = 0; ni < 4; ni++)
                acc[mi][ni] = __builtin_amdgcn_mfma_f32_16x16x32_bf16(af[mi], bf[ni], acc[mi][ni], 0, 0, 0);
        __syncthreads();
        cur ^= 1;
    }

    #pragma unroll
    for (int ni = 0; ni < 4; ni++) {
        const int col = n0 + wn + ni * 16 + lr;
        const float bv = bias ? bias[col] : 0.f;
        #pragma unroll
        for (int mi = 0; mi < 4; mi++)
            #pragma unroll
            for (int r = 0; r < 4; r++)
                C[(size_t)(m0 + wm + mi * 16 + lg * 4 + r) * N + col] = acc[mi][ni][r] + bv;
    }
}

// ---------------- grouped causal conv1 -> bf16 padded [b][SP][CH] (rows 0,1 zero) ----------------
__global__ __launch_bounds__(256)
void conv1_grouped(const float* __restrict__ qkv, int coloff,
                   const float* __restrict__ w, const float* __restrict__ bias,
                   unsigned short* __restrict__ out, int CH)
{
    const int t0 = blockIdx.x * 64;
    const int b  = blockIdx.y;
    const int g  = blockIdx.z;
    __shared__ float xs[66][64];
    for (int idx = threadIdx.x; idx < 66 * 64; idx += 256) {
        const int i = idx >> 6, ic = idx & 63;
        const int tt = t0 + i - 2;
        xs[i][ic] = (tt >= 0) ? qkv[(size_t)(b * SEQ + tt) * QKVN + coloff + g * 64 + ic] : 0.f;
    }
    __syncthreads();
    const int oc = threadIdx.x & 63;
    const int ibase = (threadIdx.x >> 6) * 16;
    float acc[16];
    const float bv = bias[g * 64 + oc];
    #pragma unroll
    for (int i = 0; i < 16; i++) acc[i] = bv;
    const float* wp = w + (size_t)(g * 64 + oc) * 192;
    for (int ic = 0; ic < 64; ic++) {
        const float w0 = wp[ic * 3 + 0], w1 = wp[ic * 3 + 1], w2 = wp[ic * 3 + 2];
        float xv[18];
        #pragma unroll
        for (int r = 0; r < 18; r++) xv[r] = xs[ibase + r][ic];
        #pragma unroll
        for (int i = 0; i < 16; i++) acc[i] += w0 * xv[i] + w1 * xv[i + 1] + w2 * xv[i + 2];
    }
    #pragma unroll
    for (int i = 0; i < 16; i++)
        out[((size_t)b * SP + 2 + t0 + ibase + i) * CH + g * 64 + oc] = f2bf(acc[i]);
}

// ---------------- head means + shifted-v build (row-major bf16) ----------------
__global__ __launch_bounds__(64)
void meanv_kernel(const float* __restrict__ qkv, float* __restrict__ qmean,
                  float* __restrict__ kmean, unsigned short* __restrict__ vRow)
{
    const int t = blockIdx.x, d = threadIdx.x;
    const int b = t >> 11, s = t & (SEQ - 1);
    const float* row = qkv + (size_t)t * QKVN;
    float qs = 0.f;
    #pragma unroll
    for (int h = 0; h < NH; h++) qs += row[h * 64 + d];
    qmean[t * 64 + d] = qs * (1.f / NH);
    float ks = 0.f;
    #pragma unroll
    for (int h = 0; h < NKV; h++) ks += row[LATENT + h * 64 + d];
    kmean[t * 64 + d] = ks * (1.f / NKV);
    #pragma unroll
    for (int g = 0; g < NKV; g++) {
        const int c = g * 64 + d;
        float v;
        if (c < 128) v = row[LATENT + KVD + c];
        else         v = (s > 0) ? qkv[(size_t)(t - 1) * QKVN + LATENT + KVD + 128 + (c - 128)] : 0.f;
        vRow[((size_t)(b * NKV + g) * SEQ + s) * 64 + d] = f2bf(v);
    }
}

// ---------------- V transpose to d-major: vTb[bg][d][S] ----------------
__global__ __launch_bounds__(256)
void vtrans(const unsigned short* __restrict__ vRow, unsigned short* __restrict__ vTb)
{
    const int s0 = blockIdx.x * 64;
    const int bg = blockIdx.y;
    __shared__ unsigned short t[64][72];
    const int tid = threadIdx.x;
    {
        const int r = tid >> 2, c0 = (tid & 3) * 16;
        const unsigned short* p = vRow + ((size_t)bg * SEQ + s0 + r) * 64 + c0;
        const short8v a = *reinterpret_cast<const short8v*>(p);
        const short8v bv = *reinterpret_cast<const short8v*>(p + 8);
        #pragma unroll
        for (int j = 0; j < 8; j++) { t[r][c0 + j] = (unsigned short)a[j]; t[r][c0 + 8 + j] = (unsigned short)bv[j]; }
    }
    __syncthreads();
    {
        const int d = tid >> 2, ss = (tid & 3) * 16;
        short8v o0, o1;
        #pragma unroll
        for (int j = 0; j < 8; j++) { o0[j] = (short)t[ss + j][d]; o1[j] = (short)t[ss + 8 + j][d]; }
        unsigned short* op = vTb + ((size_t)bg * 64 + d) * SEQ + s0 + ss;
        *reinterpret_cast<short8v*>(op) = o0;
        *reinterpret_cast<short8v*>(op + 8) = o1;
    }
}

// ---------------- fused conv2-partial merge + bias, +0.5*mean, l2norm, rope(table) -> bf16 ----------------
__global__ __launch_bounds__(64)
void qk_final(const float* __restrict__ qc2a, const float* __restrict__ qc2b,
              const float* __restrict__ kc2a, const float* __restrict__ kc2b,
              const float* __restrict__ qbias, const float* __restrict__ kbias,
              const float* __restrict__ qmean, const float* __restrict__ kmean,
              const float* __restrict__ key_temp, const float2* __restrict__ rtab,
              unsigned short* __restrict__ qTb, unsigned short* __restrict__ kTb)
{
    const int t = blockIdx.x, hh = blockIdx.y, d = threadIdx.x;
    const int b = t >> 11, s = t & (SEQ - 1);
    float val;
    if (hh < NH) {
        const size_t off = (size_t)t * LATENT + hh * 64 + d;
        val = qc2a[off] + qc2b[off] + qbias[hh * 64 + d] + 0.5f * kmean[t * 64 + d];
    } else {
        const size_t off = (size_t)t * KVD + (hh - NH) * 64 + d;
        val = kc2a[off] + kc2b[off] + kbias[(hh - NH) * 64 + d] + 0.5f * qmean[t * 64 + d];
    }
    float ss = val * val;
    #pragma unroll
    for (int off = 32; off >= 1; off >>= 1) ss += __shfl_xor(ss, off);
    const float n = sqrtf(ss);
    val = val / fmaxf(n, 1e-12f);
    if (hh >= NH) val *= key_temp[0];
    const float2 cs = rtab[s * 32 + (d >> 1)];
    const float cv = cs.x, sv = cs.y;
    const float partner = __shfl_xor(val, 1);
    const float x1 = (d & 1) ? partner : val;
    const float x2 = (d & 1) ? val : partner;
    const float o = (d & 1) ? (x1 * sv + x2 * cv) : (x1 * cv - x2 * sv);
    if (hh < NH) qTb[((size_t)(b * NH + hh) * SEQ + s) * 64 + d] = f2bf(o);
    else         kTb[((size_t)(b * NKV + (hh - NH)) * SEQ + s) * 64 + d] = f2bf(o);
}

// ---------------- MFMA causal GQA attention: 4-wave block shares K/V via LDS, BK=64 ----------------
// Work-balanced dispatch (R10); per phase the block stages a 64-key K+V super-tile (16 chunks),
// halving barrier count vs BK=32. Swapped QK^T + cvt_pk/shfl P-path (R7-verified).
__global__ __launch_bounds__(256)
void attn_mfma(const unsigned short* __restrict__ qTb, const unsigned short* __restrict__ kTb,
               const unsigned short* __restrict__ vTb, unsigned short* __restrict__ attn_out)
{
    const int wg = blockIdx.x;
    int bh, blk;
    if (wg < 256) {
        const int xcd = wg & 7, i = wg >> 3;
        bh = (xcd << 2) | (i >> 3);
        blk = 15 - (i & 7);          // 8..15
    } else {
        const int u = wg - 256;
        const int xcd = u & 7, i = u >> 3;
        bh = (xcd << 2) | (i >> 3);
        blk = i & 7;                 // 0..7
    }
    const int b = bh >> 4, h = bh & 15, g = h >> 2;
    const int tid = threadIdx.x;
    const int wave = tid >> 6, lane = tid & 63;
    const int lg = lane >> 4, lr = lane & 15;
    const int qt = blk * 4 + wave;
    const int q0 = qt * 32;
    const int ctot2 = (blk + 1) * 2;     // 64-key phases

    // chunks: st*8 + {K: kt*2+dc (0..3), V: 4+dt}; st = 32-key sub-tile 0/1
    __shared__ __align__(16) unsigned short SB[2][16][512];

    short8v qf[2][2];
    const unsigned short* qbase = qTb + ((size_t)(b * NH + h) * SEQ + q0) * 64;
    #pragma unroll
    for (int mf = 0; mf < 2; mf++)
        #pragma unroll
        for (int dc = 0; dc < 2; dc++)
            qf[mf][dc] = *reinterpret_cast<const short8v*>(qbase + (size_t)(mf * 16 + lr) * 64 + dc * 32 + lg * 8);

    f32x4 acc[2][4];
    float lsum[2] = {0.f, 0.f};
    #pragma unroll
    for (int mf = 0; mf < 2; mf++)
        #pragma unroll
        for (int dt = 0; dt < 4; dt++) acc[mf][dt] = (f32x4){0.f, 0.f, 0.f, 0.f};

    const unsigned short* kbase = kTb + (size_t)(b * NKV + g) * SEQ * 64;
    const unsigned short* vbase = vTb + (size_t)(b * NKV + g) * 64 * SEQ;
    const float EC = 0.125f * 1.44269504f;
    const int src01 = ((lg & 1) << 5) + lr;
    const int src23 = src01 + 16;
    const bool hi = (lg >= 2);

    // wave w stages chunks 4w..4w+3 of the 64-key super-tile
    auto stage64 = [&](int buf, int cc) {
        const int kb = cc * 64;
        #pragma unroll
        for (int i = 0; i < 4; i++) {
            const int ch = wave * 4 + i;
            const int st = ch >> 3, chl = ch & 7;
            const int k0 = kb + st * 32;
            const unsigned short* src;
            if (chl < 4) src = kbase + (size_t)(k0 + (chl >> 1) * 16 + lr) * 64 + (chl & 1) * 32 + lg * 8;
            else         src = vbase + (size_t)((chl - 4) * 16 + lr) * SEQ + k0 + lg * 8;
            gload_lds16(src, &SB[buf][ch][lane * 8]);
        }
    };

    stage64(0, 0);
    __syncthreads();
    int cur = 0;
    for (int cc = 0; cc < ctot2; ++cc) {
        if (cc + 1 < ctot2) stage64(cur ^ 1, cc + 1);
        #pragma unroll
        for (int st = 0; st < 2; ++st) {
            const int c = cc * 2 + st;
            if (c > qt) continue;
            const int k0 = c * 32;
            short8v kf[2][2], vf[4];
            #pragma unroll
            for (int kt = 0; kt < 2; kt++)
                #pragma unroll
                for (int dc = 0; dc < 2; dc++)
                    kf[kt][dc] = *reinterpret_cast<const short8v*>(&SB[cur][st * 8 + kt * 2 + dc][lane * 8]);
            #pragma unroll
            for (int dt = 0; dt < 4; dt++)
                vf[dt] = *reinterpret_cast<const short8v*>(&SB[cur][st * 8 + 4 + dt][lane * 8]);

            const bool diag = (c == qt);
            #pragma unroll
            for (int mf = 0; mf < 2; mf++) {
                f32x4 z0 = (f32x4){0.f, 0.f, 0.f, 0.f}, z1 = (f32x4){0.f, 0.f, 0.f, 0.f};
                __builtin_amdgcn_s_setprio(1);
                z0 = __builtin_amdgcn_mfma_f32_16x16x32_bf16(kf[0][0], qf[mf][0], z0, 0, 0, 0);
                z0 = __builtin_amdgcn_mfma_f32_16x16x32_bf16(kf[0][1], qf[mf][1], z0, 0, 0, 0);
                z1 = __builtin_amdgcn_mfma_f32_16x16x32_bf16(kf[1][0], qf[mf][0], z1, 0, 0, 0);
                z1 = __builtin_amdgcn_mfma_f32_16x16x32_bf16(kf[1][1], qf[mf][1], z1, 0, 0, 0);
                __builtin_amdgcn_s_setprio(0);
                float p0[4], p1[4];
                #pragma unroll
                for (int r = 0; r < 4; r++) {
                    p0[r] = exp2f(z0[r] * EC);
                    p1[r] = exp2f(z1[r] * EC);
                }
                if (diag) {
                    const int q = q0 + mf * 16 + lr;
                    #pragma unroll
                    for (int r = 0; r < 4; r++) {
                        if (k0 + 4 * lg + r > q)      p0[r] = 0.f;
                        if (k0 + 16 + 4 * lg + r > q) p1[r] = 0.f;
                    }
                }
                lsum[mf] += (p0[0] + p0[1]) + (p0[2] + p0[3]) + (p1[0] + p1[1]) + (p1[2] + p1[3]);
                const unsigned W00 = cvt_pk_bf16(p0[0], p0[1]);
                const unsigned W01 = cvt_pk_bf16(p0[2], p0[3]);
                const unsigned W10 = cvt_pk_bf16(p1[0], p1[1]);
                const unsigned W11 = cvt_pk_bf16(p1[2], p1[3]);
                const unsigned a0 = __shfl(W00, src01), b0 = __shfl(W10, src01);
                const unsigned a1 = __shfl(W01, src01), b1 = __shfl(W11, src01);
                const unsigned a2 = __shfl(W00, src23), b2 = __shfl(W10, src23);
                const unsigned a3 = __shfl(W01, src23), b3 = __shfl(W11, src23);
                uint4v pw;
                pw.x = hi ? b0 : a0;
                pw.y = hi ? b1 : a1;
                pw.z = hi ? b2 : a2;
                pw.w = hi ? b3 : a3;
                const short8v pa = __builtin_bit_cast(short8v, pw);
                __builtin_amdgcn_s_setprio(1);
                #pragma unroll
                for (int dt = 0; dt < 4; dt++)
                    acc[mf][dt] = __builtin_amdgcn_mfma_f32_16x16x32_bf16(pa, vf[dt], acc[mf][dt], 0, 0, 0);
                __builtin_amdgcn_s_setprio(0);
            }
        }
        __syncthreads();
        cur ^= 1;
    }

    float den[2];
    #pragma unroll
    for (int mf = 0; mf < 2; mf++) {
        float s = lsum[mf];
        s += __shfl_xor(s, 16); s += __shfl_xor(s, 32);
        den[mf] = s;
    }

    #pragma unroll
    for (int mf = 0; mf < 2; mf++) {
        float dinv[4];
        #pragma unroll
        for (int r = 0; r < 4; r++) dinv[r] = 1.f / __shfl(den[mf], 4 * lg + r);
        #pragma unroll
        for (int dt = 0; dt < 4; dt++)
            #pragma unroll
            for (int r = 0; r < 4; r++) {
                const int q = q0 + mf * 16 + 4 * lg + r;
                attn_out[(size_t)(b * SEQ + q) * LATENT + h * 64 + dt * 16 + lr] = f2bf(acc[mf][dt][r] * dinv[r]);
            }
    }
}

extern "C" void kernel_launch(void* const* d_in, const int* in_sizes, int n_in,
                              void* d_out, int out_size, void* d_ws, size_t ws_size,
                              hipStream_t stream)
{
    const float* x       = (const float*)d_in[0];
    const float* w_qkv   = (const float*)d_in[1];
    const float* w_o     = (const float*)d_in[2];
    const float* qc1_w   = (const float*)d_in[3];
    const float* qc1_b   = (const float*)d_in[4];
    const float* qc2_w   = (const float*)d_in[5];
    const float* qc2_b   = (const float*)d_in[6];
    const float* kc1_w   = (const float*)d_in[7];
    const float* kc1_b   = (const float*)d_in[8];
    const float* kc2_w   = (const float*)d_in[9];
    const float* kc2_b   = (const float*)d_in[10];
    const float* key_temp = (const float*)d_in[11];

    // --- workspace layout (aliased by lifetime; byte offsets noted) ---
    char* wsb = (char*)d_ws;
    float* qkv = (float*)wsb;                 wsb += (size_t)BS * QKVN * 4;     // [0, 25165824)
    float* qc2 = qkv;                                                            // alias (qkv dead after conv1)
    float* kc2 = (float*)((char*)qkv + (size_t)BS * LATENT * 4);                 // [16777216, 20971520)
    unsigned short* pq  = (unsigned short*)wsb;  wsb += (size_t)NB * SP * LATENT * 2;  // [25165824, 33562624)
    unsigned short* pk  = (unsigned short*)wsb;  wsb += (size_t)NB * SP * KVD * 2;     // [33562624, 35661824)
    float* qmean = (float*)wsb;  wsb += (size_t)BS * HD * 4;                     // [35661824, 36710400)
    float* kmean = (float*)wsb;  wsb += (size_t)BS * HD * 4;                     // [36710400, 37758976)
    unsigned short* qTb  = (unsigned short*)wsb;  wsb += (size_t)BS * LATENT * 2; // [37758976, 46147584)
    unsigned short* kTb  = (unsigned short*)wsb;  wsb += (size_t)BS * KVD * 2;   // [46147584, 48244736)
    unsigned short* vRow = (unsigned short*)wsb;  wsb += (size_t)BS * KVD * 2;   // [48244736, 50341888)
    unsigned short* vTb  = (unsigned short*)wsb;  wsb += (size_t)BS * KVD * 2;   // [50341888, 52439040)
    unsigned short* xb   = (unsigned short*)wsb;  wsb += (size_t)BS * DIMX * 2;  // [52439040, 85993472)
    unsigned short* attnb  = xb;                                                 // [52439040, 60827648)
    unsigned short* qc2wr  = (unsigned short*)((char*)xb + (size_t)BS * LATENT * 2);        // ..67119104
    unsigned short* kc2wr  = (unsigned short*)((char*)qc2wr + (size_t)LATENT * LATENT * 3 * 2); // ..67512320
    unsigned short* wqkvb = (unsigned short*)wsb;  wsb += (size_t)QKVN * DIMX * 2;  // [85993472, 98576384)
    unsigned short* wob   = wqkvb;

    // split-K partial placement (regions dead in stream order at their GEMM's position):
    const size_t QKV_PS = (size_t)BS * QKVN;                      // qkv p1 at qkv+M*N (pre-meanv region)
    float* qc2p1 = (float*)((char*)d_ws + 67512320);              // xb tail (dead), 16.7MB
    float* kc2p1 = (float*)((char*)d_ws + (size_t)BS * QKVN * 4); // pq region (dead after conv2-q GEMM)
    const size_t QC2_PS = (size_t)(qc2p1 - qc2);
    const size_t KC2_PS = (size_t)(kc2p1 - kc2);
    // rope table in the dead vRow region (vRow consumed by vtrans before rope_tab runs)
    float2* rtab = (float2*)vRow;   // 512KB <= 2.1MB region

    float* outp = (float*)d_out;

    // 1. casts for qkv GEMM
    cast_f2b<<<dim3(BS * DIMX / 4 / 256), 256, 0, stream>>>(x, xb, BS * DIMX / 4);
    cast_f2b<<<dim3(QKVN * DIMX / 4 / 256), 256, 0, stream>>>(w_qkv, wqkvb, QKVN * DIMX / 4);
    // 2. qkv projection, split-K=2 (768 blocks) + merge
    gemm_bf16<0><<<dim3(QKVN / 128, BS / 128, 2), 256, 0, stream>>>(xb, wqkvb, nullptr, qkv, BS, QKVN, DIMX, 0, DIMX / 2, QKV_PS);
    add2<<<dim3(BS * QKVN / 4 / 256), 256, 0, stream>>>(qkv, qkv + QKV_PS, nullptr, qkv, BS * QKVN / 4, 4);
    // 3. prep for later GEMMs (xb/wqkvb dead)
    cast_f2b<<<dim3(DIMX * LATENT / 4 / 256), 256, 0, stream>>>(w_o, wob, DIMX * LATENT / 4);
    w3reorder<<<dim3((LATENT * LATENT * 3 + 255) / 256), 256, 0, stream>>>(qc2_w, qc2wr, LATENT, LATENT);
    w3reorder<<<dim3((KVD * KVD * 3 + 255) / 256), 256, 0, stream>>>(kc2_w, kc2wr, KVD, KVD);
    // 4. means + shifted v, V transpose, rope table (into dead vRow), pads
    meanv_kernel<<<dim3(BS), 64, 0, stream>>>(qkv, qmean, kmean, vRow);
    vtrans<<<dim3(SEQ / 64, NB * NKV), 256, 0, stream>>>(vRow, vTb);
    rope_tab<<<dim3(SEQ * 32 / 256), 256, 0, stream>>>(rtab);
    zero_pad<<<dim3(16), 256, 0, stream>>>(pq, pk);
    // 5. grouped conv1 -> padded bf16
    conv1_grouped<<<dim3(SEQ / 64, NB, NH),  256, 0, stream>>>(qkv, 0,      qc1_w, qc1_b, pq, LATENT);
    conv1_grouped<<<dim3(SEQ / 64, NB, NKV), 256, 0, stream>>>(qkv, LATENT, kc1_w, kc1_b, pk, KVD);
    // 6. conv2 as split-K bf16 GEMMs; partials merged inside qk_final (no add2)
    gemm_bf16<1><<<dim3(LATENT / 128, BS / 128, 2), 256, 0, stream>>>(pq, qc2wr, nullptr, qc2, BS, LATENT, LATENT * 3, LATENT, LATENT * 3 / 2, QC2_PS);
    gemm_bf16<1><<<dim3(KVD / 128, BS / 128, 2), 256, 0, stream>>>(pk, kc2wr, nullptr, kc2, BS, KVD, KVD * 3, KVD, KVD * 3 / 2, KC2_PS);
    // 7. fused merge+bias, +0.5*mean, l2norm, rope
    qk_final<<<dim3(BS, NH + NKV), 64, 0, stream>>>(qc2, qc2p1, kc2, kc2p1, qc2_b, kc2_b,
                                                    qmean, kmean, key_temp, rtab, qTb, kTb);
    // 8. attention (work-balanced pairing, BK=64)
    attn_mfma<<<dim3(512), 256, 0, stream>>>(qTb, kTb, vTb, attnb);
    // 9. output projection (1024 blocks, 4/CU)
    gemm_bf16<0><<<dim3(DIMX / 128, BS / 128, 1), 256, 0, stream>>>(attnb, wob, nullptr, outp, BS, DIMX, LATENT, 0, LATENT, 0);
}